// Round 1
// baseline (2092.222 us; speedup 1.0000x reference)
//
#include <hip/hip_runtime.h>
#include <math.h>

// Problem constants (compile-time, from reference)
// DEG_COUNTS = [20000, 80000, 150000, 150000, 75000, 20000, 5000]
// OFF        = [0, 20000, 100000, 250000, 400000, 475000, 495000, 500000]
// N_ATOMS = 500000, BATCH = 1024, F_IN = 75

struct AdjPtrs { const int* p[6]; };

// ---------------- membership counting sort ----------------
__global__ __launch_bounds__(256) void k_zero_hist(int* __restrict__ hist) {
  int i = blockIdx.x * 256 + threadIdx.x;
  if (i < 1024) hist[i] = 0;
}

__global__ __launch_bounds__(256) void k_hist(const int* __restrict__ mem, int* __restrict__ hist) {
  __shared__ int lh[1024];
  int tid = threadIdx.x;
  for (int i = tid; i < 1024; i += 256) lh[i] = 0;
  __syncthreads();
  int stride = gridDim.x * 256;
  for (int i = blockIdx.x * 256 + tid; i < 500000; i += stride)
    atomicAdd(&lh[mem[i]], 1);
  __syncthreads();
  for (int i = tid; i < 1024; i += 256) {
    int v = lh[i];
    if (v) atomicAdd(&hist[i], v);
  }
}

__global__ __launch_bounds__(1024) void k_scan(const int* __restrict__ hist,
                                               int* __restrict__ start,
                                               int* __restrict__ cursor) {
  __shared__ int sc[1024];
  int t = threadIdx.x;
  int h = hist[t];
  sc[t] = h;
  __syncthreads();
  for (int off = 1; off < 1024; off <<= 1) {
    int v = (t >= off) ? sc[t - off] : 0;
    __syncthreads();
    sc[t] += v;
    __syncthreads();
  }
  int ex = sc[t] - h;
  start[t] = ex;
  cursor[t] = ex;
}

__global__ __launch_bounds__(256) void k_scatter(const int* __restrict__ mem,
                                                 int* __restrict__ cursor,
                                                 int* __restrict__ list) {
  int i = blockIdx.x * 256 + threadIdx.x;
  if (i < 500000) {
    int pos = atomicAdd(&cursor[mem[i]], 1);
    list[pos] = i;
  }
}

// ---------------- fused graph_conv + tanh + bn1 ----------------
// Block = 256 threads = 4 waves; 16 atoms/block (4 atoms per wave, packed float4).
// Block -> degree mapping is compile-time (all OFF divisible by 8, so tail waves
// are all-or-nothing active).
template<int F>
__global__ __launch_bounds__(256) void k_gc(
    const float* __restrict__ feat, AdjPtrs adjs,
    const float* __restrict__ Wn, const float* __restrict__ Ws,
    const float* __restrict__ bias,
    const float* __restrict__ bng, const float* __restrict__ bnb,
    const float* __restrict__ bnm, const float* __restrict__ bnv,
    float* __restrict__ out)
{
  __shared__ float Wls[F * 64];
  __shared__ float Wln[F * 64];
  __shared__ float xsq[4 * F * 4];  // [wave][k][atom_i]
  __shared__ float xnq[4 * F * 4];

  int bid = blockIdx.x;
  int d, off, end, bloc;
  if      (bid < 1250)  { d = 0; bloc = bid;         off = 0;      end = 20000;  }
  else if (bid < 6250)  { d = 1; bloc = bid - 1250;  off = 20000;  end = 100000; }
  else if (bid < 15625) { d = 2; bloc = bid - 6250;  off = 100000; end = 250000; }
  else if (bid < 25000) { d = 3; bloc = bid - 15625; off = 250000; end = 400000; }
  else if (bid < 29688) { d = 4; bloc = bid - 25000; off = 400000; end = 475000; }
  else if (bid < 30938) { d = 5; bloc = bid - 29688; off = 475000; end = 495000; }
  else                  { d = 6; bloc = bid - 30938; off = 495000; end = 500000; }
  int atom_base = off + bloc * 16;
  int tid = threadIdx.x;

  // stage weights into LDS (whole block)
  for (int i = tid; i < F * 64; i += 256) Wls[i] = Ws[d * F * 64 + i];
  if (d > 0)
    for (int i = tid; i < F * 64; i += 256) Wln[i] = Wn[(d - 1) * F * 64 + i];

  int w = tid >> 6, l = tid & 63;
  int a0 = atom_base + w * 4;
  bool active = a0 < end;

  if (active) {
    const int* ad = (d > 0) ? adjs.p[d - 1] : (const int*)0;
    for (int idx = l; idx < F * 4; idx += 64) {
      int k = idx >> 2, i = idx & 3;
      int ga = a0 + i;
      xsq[w * F * 4 + idx] = feat[ga * F + k];
      if (d > 0) {
        int la = ga - off;
        float s = 0.f;
        for (int e = 0; e < d; e++) s += feat[ad[la * d + e] * F + k];
        xnq[w * F * 4 + idx] = s;
      }
    }
  }
  __syncthreads();
  if (!active) return;

  int j = l;
  float bj  = bias[d * 64 + j];
  float scj = bng[j] * rsqrtf(bnv[j] + 1e-3f);
  float shj = bnb[j] - bnm[j] * scj;
  float acc0 = bj, acc1 = bj, acc2 = bj, acc3 = bj;
  const float* xs = &xsq[w * F * 4];
  const float* xn = &xnq[w * F * 4];

  if (d > 0) {
    for (int k = 0; k < F; k++) {
      float ws = Wls[k * 64 + j];
      float wn = Wln[k * 64 + j];
      float4 s4 = *(const float4*)(xs + k * 4);
      float4 n4 = *(const float4*)(xn + k * 4);
      acc0 += s4.x * ws + n4.x * wn;
      acc1 += s4.y * ws + n4.y * wn;
      acc2 += s4.z * ws + n4.z * wn;
      acc3 += s4.w * ws + n4.w * wn;
    }
  } else {
    for (int k = 0; k < F; k++) {
      float ws = Wls[k * 64 + j];
      float4 s4 = *(const float4*)(xs + k * 4);
      acc0 += s4.x * ws;
      acc1 += s4.y * ws;
      acc2 += s4.z * ws;
      acc3 += s4.w * ws;
    }
  }
  int ob = a0 * 64 + j;
  out[ob]       = tanhf(acc0) * scj + shj;
  out[ob + 64]  = tanhf(acc1) * scj + shj;
  out[ob + 128] = tanhf(acc2) * scj + shj;
  out[ob + 192] = tanhf(acc3) * scj + shj;
}

// ---------------- graph_pool: out = max(self, neighbors) per feature ----------------
// One wave per atom (64 lanes = 64 features) -> degree branch is wave-uniform.
__global__ __launch_bounds__(256) void k_pool(const float* __restrict__ in, AdjPtrs adjs,
                                              float* __restrict__ out)
{
  int t = blockIdx.x * 256 + threadIdx.x;   // grid exactly covers 500000*64
  int atom = t >> 6, j = t & 63;
  int d, off;
  if      (atom < 20000)  { d = 0; off = 0;      }
  else if (atom < 100000) { d = 1; off = 20000;  }
  else if (atom < 250000) { d = 2; off = 100000; }
  else if (atom < 400000) { d = 3; off = 250000; }
  else if (atom < 475000) { d = 4; off = 400000; }
  else if (atom < 495000) { d = 5; off = 475000; }
  else                    { d = 6; off = 495000; }
  float v = in[t];
  if (d > 0) {
    const int* ad = adjs.p[d - 1];
    int la = atom - off;
    for (int e = 0; e < d; e++) v = fmaxf(v, in[ad[la * d + e] * 64 + j]);
  }
  out[t] = v;
}

// ---------------- fused dense1 + tanh + bn3 + segment sum/max + tanh ----------------
// One block (128 threads) per batch element; d1_W (64x128) in LDS; h5 never materialized.
__global__ __launch_bounds__(128) void k_gather_dense1(
    const float* __restrict__ h, const int* __restrict__ list,
    const int* __restrict__ start, const int* __restrict__ hist,
    const float* __restrict__ W, const float* __restrict__ bvec,
    const float* __restrict__ g3, const float* __restrict__ b3,
    const float* __restrict__ m3, const float* __restrict__ v3,
    float* __restrict__ g)
{
  __shared__ float Wl[64 * 128];
  __shared__ float rows[8 * 64];
  int b = blockIdx.x, tid = threadIdx.x;

  for (int i = tid; i < 64 * 128; i += 128) Wl[i] = W[i];
  float scj = g3[tid] * rsqrtf(v3[tid] + 1e-3f);
  float shj = b3[tid] - m3[tid] * scj;
  float bj  = bvec[tid];

  float s = 0.f, m = -INFINITY;
  int stt = start[b], cnt = hist[b];

  for (int t0 = 0; t0 < cnt; t0 += 8) {
    int nr = min(8, cnt - t0);
    __syncthreads();  // protect rows[] from previous iteration's readers
    for (int idx = tid; idx < nr * 64; idx += 128) {
      int r = idx >> 6, kk = idx & 63;
      int a = list[stt + t0 + r];
      rows[idx] = h[a * 64 + kk];
    }
    __syncthreads();
    for (int r = 0; r < nr; r++) {
      const float* x = &rows[r * 64];
      float acc = bj;
      #pragma unroll
      for (int k = 0; k < 64; k += 4) {
        float4 x4 = *(const float4*)(x + k);
        acc += x4.x * Wl[(k    ) * 128 + tid];
        acc += x4.y * Wl[(k + 1) * 128 + tid];
        acc += x4.z * Wl[(k + 2) * 128 + tid];
        acc += x4.w * Wl[(k + 3) * 128 + tid];
      }
      float v = tanhf(acc);
      v = v * scj + shj;
      s += v;
      m = fmaxf(m, v);
    }
  }
  g[b * 256 + tid]       = tanhf(s);
  g[b * 256 + 128 + tid] = tanhf(m);
}

// ---------------- dense2 -> sigmoid -> dense3 ----------------
__global__ __launch_bounds__(64) void k_dense23(
    const float* __restrict__ g, const float* __restrict__ W2,
    const float* __restrict__ b2, const float* __restrict__ W3,
    const float* __restrict__ b3, float* __restrict__ out)
{
  __shared__ float gr[256];
  int b = blockIdx.x, j = threadIdx.x;
  ((float4*)gr)[j] = ((const float4*)(g + b * 256))[j];
  __syncthreads();
  float acc = b2[j];
  #pragma unroll 8
  for (int k = 0; k < 256; k++) acc += gr[k] * W2[k * 64 + j];
  float sg = 1.f / (1.f + expf(-acc));
  float p = sg * W3[j];
  #pragma unroll
  for (int off = 32; off >= 1; off >>= 1) p += __shfl_xor(p, off);
  if (j == 0) out[b] = p + b3[0];
}

// ---------------- launch ----------------
extern "C" void kernel_launch(void* const* d_in, const int* in_sizes, int n_in,
                              void* d_out, int out_size, void* d_ws, size_t ws_size,
                              hipStream_t stream) {
  const float* feat = (const float*)d_in[0];
  const int*   mem  = (const int*)d_in[1];
  AdjPtrs adjs;
  for (int i = 0; i < 6; i++) adjs.p[i] = (const int*)d_in[2 + i];
  const float* gc1_Wn = (const float*)d_in[8];
  const float* gc1_Ws = (const float*)d_in[9];
  const float* gc1_b  = (const float*)d_in[10];
  const float* gc2_Wn = (const float*)d_in[11];
  const float* gc2_Ws = (const float*)d_in[12];
  const float* gc2_b  = (const float*)d_in[13];
  const float* bn1g = (const float*)d_in[14];
  const float* bn1b = (const float*)d_in[15];
  const float* bn1m = (const float*)d_in[16];
  const float* bn1v = (const float*)d_in[17];
  const float* bn3g = (const float*)d_in[18];
  const float* bn3b = (const float*)d_in[19];
  const float* bn3m = (const float*)d_in[20];
  const float* bn3v = (const float*)d_in[21];
  const float* d1W = (const float*)d_in[22];
  const float* d1b = (const float*)d_in[23];
  const float* d2W = (const float*)d_in[24];
  const float* d2b = (const float*)d_in[25];
  const float* d3W = (const float*)d_in[26];
  const float* d3b = (const float*)d_in[27];
  float* out = (float*)d_out;

  // workspace layout (bytes): hA 128M | hB 128M | g 1M | hist/start/cursor 4K each | list 2M
  char* w = (char*)d_ws;
  float* hA    = (float*)(w);
  float* hB    = (float*)(w + 128000000LL);
  float* g     = (float*)(w + 256000000LL);
  int* hist    = (int*)(w + 257048576LL);
  int* start   = (int*)(w + 257052672LL);
  int* cursor  = (int*)(w + 257056768LL);
  int* list    = (int*)(w + 257060864LL);

  // membership counting sort (ws is re-poisoned every call -> recompute)
  k_zero_hist<<<4, 256, 0, stream>>>(hist);
  k_hist<<<512, 256, 0, stream>>>(mem, hist);
  k_scan<<<1, 1024, 0, stream>>>(hist, start, cursor);
  k_scatter<<<1954, 256, 0, stream>>>(mem, cursor, list);

  // main pipeline
  k_gc<75><<<31251, 256, 0, stream>>>(feat, adjs, gc1_Wn, gc1_Ws, gc1_b,
                                      bn1g, bn1b, bn1m, bn1v, hA);
  k_pool<<<125000, 256, 0, stream>>>(hA, adjs, hB);
  k_gc<64><<<31251, 256, 0, stream>>>(hB, adjs, gc2_Wn, gc2_Ws, gc2_b,
                                      bn1g, bn1b, bn1m, bn1v, hA);
  k_pool<<<125000, 256, 0, stream>>>(hA, adjs, hB);
  k_gather_dense1<<<1024, 128, 0, stream>>>(hB, list, start, hist, d1W, d1b,
                                            bn3g, bn3b, bn3m, bn3v, g);
  k_dense23<<<1024, 64, 0, stream>>>(g, d2W, d2b, d3W, d3b, out);
}

// Round 2
// 1471.222 us; speedup vs baseline: 1.4221x; 1.4221x over previous
//
#include <hip/hip_runtime.h>
#include <math.h>

// DEG_COUNTS = [20000, 80000, 150000, 150000, 75000, 20000, 5000]
// OFF        = [0, 20000, 100000, 250000, 400000, 475000, 495000, 500000]
// N_ATOMS = 500000, BATCH = 1024, F_IN = 75

struct AdjPtrs { const int* p[6]; };

// ---------------- membership counting sort ----------------
__global__ __launch_bounds__(256) void k_zero_hist(int* __restrict__ hist) {
  int i = blockIdx.x * 256 + threadIdx.x;
  if (i < 1024) hist[i] = 0;
}

__global__ __launch_bounds__(256) void k_hist(const int* __restrict__ mem, int* __restrict__ hist) {
  __shared__ int lh[1024];
  int tid = threadIdx.x;
  for (int i = tid; i < 1024; i += 256) lh[i] = 0;
  __syncthreads();
  int stride = gridDim.x * 256;
  for (int i = blockIdx.x * 256 + tid; i < 500000; i += stride)
    atomicAdd(&lh[mem[i]], 1);
  __syncthreads();
  for (int i = tid; i < 1024; i += 256) {
    int v = lh[i];
    if (v) atomicAdd(&hist[i], v);
  }
}

__global__ __launch_bounds__(1024) void k_scan(const int* __restrict__ hist,
                                               int* __restrict__ start,
                                               int* __restrict__ cursor) {
  __shared__ int sc[1024];
  int t = threadIdx.x;
  int h = hist[t];
  sc[t] = h;
  __syncthreads();
  for (int off = 1; off < 1024; off <<= 1) {
    int v = (t >= off) ? sc[t - off] : 0;
    __syncthreads();
    sc[t] += v;
    __syncthreads();
  }
  int ex = sc[t] - h;
  start[t] = ex;
  cursor[t] = ex;
}

__global__ __launch_bounds__(256) void k_scatter(const int* __restrict__ mem,
                                                 int* __restrict__ cursor,
                                                 int* __restrict__ list) {
  int i = blockIdx.x * 256 + threadIdx.x;
  if (i < 500000) {
    int pos = atomicAdd(&cursor[mem[i]], 1);
    list[pos] = i;
  }
}

// ---------------- fused graph_conv + tanh + bn1 ----------------
// Block = 256 threads = 4 waves; 32 atoms/block (8 per wave).
// Phase 1: stage weights (float4), self rows (contiguous float4), adjacency (LDS).
// Phase 2: cooperative neighbor gather-sum, degree-templated (unrolled -> ILP).
// Phase 3: dense FMA compute, x broadcast from LDS, weights conflict-free.

template<int F, int D>
__device__ inline void gather_n(const float* __restrict__ feat, const int* __restrict__ aidx,
                                float* __restrict__ xn, int na, int tid) {
  if (F == 75) {
    for (int idx = tid; idx < na * 75; idx += 256) {
      int a = idx / 75, k = idx - a * 75;
      float s = 0.f;
      #pragma unroll
      for (int e = 0; e < D; e++) s += feat[aidx[a * D + e] * 75 + k];
      xn[(a >> 3) * 75 * 8 + k * 8 + (a & 7)] = s;
    }
  } else {
    const float4* in4 = (const float4*)feat;
    for (int idx = tid; idx < na * 16; idx += 256) {
      int a = idx >> 4, k4 = idx & 15;
      float4 s = make_float4(0.f, 0.f, 0.f, 0.f);
      #pragma unroll
      for (int e = 0; e < D; e++) {
        float4 u = in4[aidx[a * D + e] * 16 + k4];
        s.x += u.x; s.y += u.y; s.z += u.z; s.w += u.w;
      }
      int base = (a >> 3) * 64 * 8 + (k4 * 4) * 8 + (a & 7);
      xn[base] = s.x; xn[base + 8] = s.y; xn[base + 16] = s.z; xn[base + 24] = s.w;
    }
  }
}

template<int F>
__global__ __launch_bounds__(256) void k_gc(
    const float* __restrict__ feat, AdjPtrs adjs,
    const float* __restrict__ Wn, const float* __restrict__ Ws,
    const float* __restrict__ bias,
    const float* __restrict__ bng, const float* __restrict__ bnb,
    const float* __restrict__ bnm, const float* __restrict__ bnv,
    float* __restrict__ out)
{
  __shared__ float Wls[F * 64];
  __shared__ float Wln[F * 64];
  __shared__ float xs[4 * F * 8];
  __shared__ float xn[4 * F * 8];
  __shared__ int aidx[32 * 6];

  int bid = blockIdx.x;
  int d, off, end, bloc;
  if      (bid < 625)   { d = 0; bloc = bid;         off = 0;      end = 20000;  }
  else if (bid < 3125)  { d = 1; bloc = bid - 625;   off = 20000;  end = 100000; }
  else if (bid < 7813)  { d = 2; bloc = bid - 3125;  off = 100000; end = 250000; }
  else if (bid < 12501) { d = 3; bloc = bid - 7813;  off = 250000; end = 400000; }
  else if (bid < 14845) { d = 4; bloc = bid - 12501; off = 400000; end = 475000; }
  else if (bid < 15470) { d = 5; bloc = bid - 14845; off = 475000; end = 495000; }
  else                  { d = 6; bloc = bid - 15470; off = 495000; end = 500000; }
  int abase = off + bloc * 32;
  int na = min(32, end - abase);
  int tid = threadIdx.x;

  // ---- phase 1: weights + self rows + adjacency ----
  {
    const float4* ws4 = (const float4*)(Ws + d * F * 64);
    float4* wl4 = (float4*)Wls;
    for (int i = tid; i < F * 16; i += 256) wl4[i] = ws4[i];
    if (d > 0) {
      const float4* wn4 = (const float4*)(Wn + (d - 1) * F * 64);
      float4* wl4n = (float4*)Wln;
      for (int i = tid; i < F * 16; i += 256) wl4n[i] = wn4[i];
      const int* adj = adjs.p[d - 1] + (abase - off) * d;
      for (int i = tid; i < na * d; i += 256) aidx[i] = adj[i];
    }
    if (F == 75) {
      const float4* src = (const float4*)(feat + abase * 75);
      int nf4 = na * 75 / 4;  // na is always a multiple of 8 -> divisible
      for (int i = tid; i < nf4; i += 256) {
        float4 v = src[i];
        int e = 4 * i;
        #pragma unroll
        for (int c = 0; c < 4; c++) {
          int ee = e + c;
          int a = ee / 75, k = ee - a * 75;
          xs[(a >> 3) * 75 * 8 + k * 8 + (a & 7)] = (&v.x)[c];
        }
      }
    } else {
      const float4* src = (const float4*)(feat + abase * 64);
      for (int i = tid; i < na * 16; i += 256) {
        float4 v = src[i];
        int a = i >> 4, kb = (i & 15) * 4;
        int base = (a >> 3) * 64 * 8 + kb * 8 + (a & 7);
        xs[base] = v.x; xs[base + 8] = v.y; xs[base + 16] = v.z; xs[base + 24] = v.w;
      }
    }
  }
  __syncthreads();

  // ---- phase 2: neighbor gather-sum (degree-templated) ----
  if (d > 0) {
    switch (d) {
      case 1: gather_n<F, 1>(feat, aidx, xn, na, tid); break;
      case 2: gather_n<F, 2>(feat, aidx, xn, na, tid); break;
      case 3: gather_n<F, 3>(feat, aidx, xn, na, tid); break;
      case 4: gather_n<F, 4>(feat, aidx, xn, na, tid); break;
      case 5: gather_n<F, 5>(feat, aidx, xn, na, tid); break;
      default: gather_n<F, 6>(feat, aidx, xn, na, tid); break;
    }
  }
  __syncthreads();

  // ---- phase 3: dense compute ----
  int w = tid >> 6, j = tid & 63;
  int a0 = abase + w * 8;
  float bj  = bias[d * 64 + j];
  float scj = bng[j] * rsqrtf(bnv[j] + 1e-3f);
  float shj = bnb[j] - bnm[j] * scj;
  float acc[8];
  #pragma unroll
  for (int i = 0; i < 8; i++) acc[i] = bj;

  const float* xsw = xs + w * F * 8;
  const float* xnw = xn + w * F * 8;

  if (d > 0) {
    for (int k = 0; k < F; k++) {
      float ws = Wls[k * 64 + j];
      float wn = Wln[k * 64 + j];
      float4 sa = *(const float4*)(xsw + k * 8);
      float4 sb = *(const float4*)(xsw + k * 8 + 4);
      float4 ga = *(const float4*)(xnw + k * 8);
      float4 gb = *(const float4*)(xnw + k * 8 + 4);
      acc[0] += sa.x * ws + ga.x * wn;
      acc[1] += sa.y * ws + ga.y * wn;
      acc[2] += sa.z * ws + ga.z * wn;
      acc[3] += sa.w * ws + ga.w * wn;
      acc[4] += sb.x * ws + gb.x * wn;
      acc[5] += sb.y * ws + gb.y * wn;
      acc[6] += sb.z * ws + gb.z * wn;
      acc[7] += sb.w * ws + gb.w * wn;
    }
  } else {
    for (int k = 0; k < F; k++) {
      float ws = Wls[k * 64 + j];
      float4 sa = *(const float4*)(xsw + k * 8);
      float4 sb = *(const float4*)(xsw + k * 8 + 4);
      acc[0] += sa.x * ws; acc[1] += sa.y * ws;
      acc[2] += sa.z * ws; acc[3] += sa.w * ws;
      acc[4] += sb.x * ws; acc[5] += sb.y * ws;
      acc[6] += sb.z * ws; acc[7] += sb.w * ws;
    }
  }
  #pragma unroll
  for (int i = 0; i < 8; i++) {
    int a = a0 + i;
    if (a < end) out[a * 64 + j] = tanhf(acc[i]) * scj + shj;
  }
}

// ---------------- graph_pool (degree-templated, float4) ----------------
template<int D>
__device__ inline float4 pool_acc(const float4* __restrict__ in4, const int* __restrict__ ad,
                                  int k4, float4 v) {
  #pragma unroll
  for (int e = 0; e < D; e++) {
    float4 u = in4[ad[e] * 16 + k4];
    v.x = fmaxf(v.x, u.x); v.y = fmaxf(v.y, u.y);
    v.z = fmaxf(v.z, u.z); v.w = fmaxf(v.w, u.w);
  }
  return v;
}

__global__ __launch_bounds__(256) void k_pool(const float4* __restrict__ in4, AdjPtrs adjs,
                                              float4* __restrict__ out4)
{
  int t = blockIdx.x * 256 + threadIdx.x;  // covers 500000*16 exactly
  int atom = t >> 4, k4 = t & 15;
  int d, off;
  if      (atom < 20000)  { d = 0; off = 0;      }
  else if (atom < 100000) { d = 1; off = 20000;  }
  else if (atom < 250000) { d = 2; off = 100000; }
  else if (atom < 400000) { d = 3; off = 250000; }
  else if (atom < 475000) { d = 4; off = 400000; }
  else if (atom < 495000) { d = 5; off = 475000; }
  else                    { d = 6; off = 495000; }
  float4 v = in4[t];
  if (d > 0) {
    const int* ad = adjs.p[d - 1] + (atom - off) * d;
    switch (d) {
      case 1: v = pool_acc<1>(in4, ad, k4, v); break;
      case 2: v = pool_acc<2>(in4, ad, k4, v); break;
      case 3: v = pool_acc<3>(in4, ad, k4, v); break;
      case 4: v = pool_acc<4>(in4, ad, k4, v); break;
      case 5: v = pool_acc<5>(in4, ad, k4, v); break;
      default: v = pool_acc<6>(in4, ad, k4, v); break;
    }
  }
  out4[t] = v;
}

// ---------------- fused dense1 + tanh + bn3 + segment sum/max + tanh ----------------
// One block (128 threads) per batch element; d1_W column held in 64 VGPRs.
__global__ __launch_bounds__(128) void k_gather_dense1(
    const float* __restrict__ h, const int* __restrict__ list,
    const int* __restrict__ start, const int* __restrict__ hist,
    const float* __restrict__ W, const float* __restrict__ bvec,
    const float* __restrict__ g3, const float* __restrict__ b3,
    const float* __restrict__ m3, const float* __restrict__ v3,
    float* __restrict__ g)
{
  __shared__ float rows[8 * 64];
  int b = blockIdx.x, tid = threadIdx.x;

  float Wc[64];
  #pragma unroll
  for (int k = 0; k < 64; k++) Wc[k] = W[k * 128 + tid];
  float scj = g3[tid] * rsqrtf(v3[tid] + 1e-3f);
  float shj = b3[tid] - m3[tid] * scj;
  float bj  = bvec[tid];

  float s = 0.f, m = -INFINITY;
  int stt = start[b], cnt = hist[b];

  for (int t0 = 0; t0 < cnt; t0 += 8) {
    int nr = min(8, cnt - t0);
    __syncthreads();
    if (tid < nr * 16) {
      int r = tid >> 4, c = tid & 15;
      int a = list[stt + t0 + r];
      ((float4*)(rows + r * 64))[c] = ((const float4*)(h + a * 64))[c];
    }
    __syncthreads();
    for (int r = 0; r < nr; r++) {
      const float* x = rows + r * 64;
      float a0 = bj, a1 = 0.f, a2 = 0.f, a3 = 0.f;
      #pragma unroll
      for (int k = 0; k < 64; k += 4) {
        float4 x4 = *(const float4*)(x + k);
        a0 += x4.x * Wc[k];
        a1 += x4.y * Wc[k + 1];
        a2 += x4.z * Wc[k + 2];
        a3 += x4.w * Wc[k + 3];
      }
      float v = tanhf((a0 + a1) + (a2 + a3));
      v = v * scj + shj;
      s += v;
      m = fmaxf(m, v);
    }
  }
  g[b * 256 + tid]       = tanhf(s);
  g[b * 256 + 128 + tid] = tanhf(m);
}

// ---------------- dense2 -> sigmoid -> dense3 ----------------
__global__ __launch_bounds__(64) void k_dense23(
    const float* __restrict__ g, const float* __restrict__ W2,
    const float* __restrict__ b2, const float* __restrict__ W3,
    const float* __restrict__ b3, float* __restrict__ out)
{
  __shared__ float gr[256];
  int b = blockIdx.x, j = threadIdx.x;
  ((float4*)gr)[j] = ((const float4*)(g + b * 256))[j];
  __syncthreads();
  float acc = b2[j];
  #pragma unroll 8
  for (int k = 0; k < 256; k++) acc += gr[k] * W2[k * 64 + j];
  float sg = 1.f / (1.f + expf(-acc));
  float p = sg * W3[j];
  #pragma unroll
  for (int off = 32; off >= 1; off >>= 1) p += __shfl_xor(p, off);
  if (j == 0) out[b] = p + b3[0];
}

// ---------------- launch ----------------
extern "C" void kernel_launch(void* const* d_in, const int* in_sizes, int n_in,
                              void* d_out, int out_size, void* d_ws, size_t ws_size,
                              hipStream_t stream) {
  const float* feat = (const float*)d_in[0];
  const int*   mem  = (const int*)d_in[1];
  AdjPtrs adjs;
  for (int i = 0; i < 6; i++) adjs.p[i] = (const int*)d_in[2 + i];
  const float* gc1_Wn = (const float*)d_in[8];
  const float* gc1_Ws = (const float*)d_in[9];
  const float* gc1_b  = (const float*)d_in[10];
  const float* gc2_Wn = (const float*)d_in[11];
  const float* gc2_Ws = (const float*)d_in[12];
  const float* gc2_b  = (const float*)d_in[13];
  const float* bn1g = (const float*)d_in[14];
  const float* bn1b = (const float*)d_in[15];
  const float* bn1m = (const float*)d_in[16];
  const float* bn1v = (const float*)d_in[17];
  const float* bn3g = (const float*)d_in[18];
  const float* bn3b = (const float*)d_in[19];
  const float* bn3m = (const float*)d_in[20];
  const float* bn3v = (const float*)d_in[21];
  const float* d1W = (const float*)d_in[22];
  const float* d1b = (const float*)d_in[23];
  const float* d2W = (const float*)d_in[24];
  const float* d2b = (const float*)d_in[25];
  const float* d3W = (const float*)d_in[26];
  const float* d3b = (const float*)d_in[27];
  float* out = (float*)d_out;

  // workspace layout (bytes): hA 128M | hB 128M | g 1M | hist/start/cursor 4K each | list 2M
  char* w = (char*)d_ws;
  float* hA    = (float*)(w);
  float* hB    = (float*)(w + 128000000LL);
  float* g     = (float*)(w + 256000000LL);
  int* hist    = (int*)(w + 257048576LL);
  int* start   = (int*)(w + 257052672LL);
  int* cursor  = (int*)(w + 257056768LL);
  int* list    = (int*)(w + 257060864LL);

  // membership counting sort
  k_zero_hist<<<4, 256, 0, stream>>>(hist);
  k_hist<<<512, 256, 0, stream>>>(mem, hist);
  k_scan<<<1, 1024, 0, stream>>>(hist, start, cursor);
  k_scatter<<<1954, 256, 0, stream>>>(mem, cursor, list);

  // main pipeline
  k_gc<75><<<15627, 256, 0, stream>>>(feat, adjs, gc1_Wn, gc1_Ws, gc1_b,
                                      bn1g, bn1b, bn1m, bn1v, hA);
  k_pool<<<31250, 256, 0, stream>>>((const float4*)hA, adjs, (float4*)hB);
  k_gc<64><<<15627, 256, 0, stream>>>(hB, adjs, gc2_Wn, gc2_Ws, gc2_b,
                                      bn1g, bn1b, bn1m, bn1v, hA);
  k_pool<<<31250, 256, 0, stream>>>((const float4*)hA, adjs, (float4*)hB);
  k_gather_dense1<<<1024, 128, 0, stream>>>(hB, list, start, hist, d1W, d1b,
                                            bn3g, bn3b, bn3m, bn3v, g);
  k_dense23<<<1024, 64, 0, stream>>>(g, d2W, d2b, d3W, d3b, out);
}

// Round 3
// 1112.128 us; speedup vs baseline: 1.8813x; 1.3229x over previous
//
#include <hip/hip_runtime.h>
#include <hip/hip_fp16.h>
#include <math.h>

// DEG_COUNTS = [20000, 80000, 150000, 150000, 75000, 20000, 5000]
// OFF        = [0, 20000, 100000, 250000, 400000, 475000, 495000, 500000]
// N_ATOMS = 500000, BATCH = 1024, F_IN = 75

struct AdjPtrs { const int* p[6]; };

typedef _Float16 f16x8 __attribute__((ext_vector_type(8)));
typedef float f32x4 __attribute__((ext_vector_type(4)));

__device__ __forceinline__ float tanh_fast(float x) {
  float ax = fabsf(x);
  float r = __expf(-2.f * ax);             // r in (0,1], never inf
  float t = 1.f - 2.f * r * __builtin_amdgcn_rcpf(1.f + r);
  return copysignf(t, x);
}

// ---------------- membership counting sort ----------------
__global__ __launch_bounds__(256) void k_zero_hist(int* __restrict__ hist) {
  int i = blockIdx.x * 256 + threadIdx.x;
  if (i < 1024) hist[i] = 0;
}

__global__ __launch_bounds__(256) void k_hist(const int* __restrict__ mem, int* __restrict__ hist) {
  __shared__ int lh[1024];
  int tid = threadIdx.x;
  for (int i = tid; i < 1024; i += 256) lh[i] = 0;
  __syncthreads();
  int stride = gridDim.x * 256;
  for (int i = blockIdx.x * 256 + tid; i < 500000; i += stride)
    atomicAdd(&lh[mem[i]], 1);
  __syncthreads();
  for (int i = tid; i < 1024; i += 256) {
    int v = lh[i];
    if (v) atomicAdd(&hist[i], v);
  }
}

__global__ __launch_bounds__(1024) void k_scan(const int* __restrict__ hist,
                                               int* __restrict__ start,
                                               int* __restrict__ cursor) {
  __shared__ int sc[1024];
  int t = threadIdx.x;
  int h = hist[t];
  sc[t] = h;
  __syncthreads();
  for (int off = 1; off < 1024; off <<= 1) {
    int v = (t >= off) ? sc[t - off] : 0;
    __syncthreads();
    sc[t] += v;
    __syncthreads();
  }
  int ex = sc[t] - h;
  start[t] = ex;
  cursor[t] = ex;
}

__global__ __launch_bounds__(256) void k_scatter(const int* __restrict__ mem,
                                                 int* __restrict__ cursor,
                                                 int* __restrict__ list) {
  int i = blockIdx.x * 256 + threadIdx.x;
  if (i < 500000) {
    int pos = atomicAdd(&cursor[mem[i]], 1);
    list[pos] = i;
  }
}

// ---------------- prep: feat fp32[500k x 75] -> fp16 padded [500k x 80] ----------------
__global__ __launch_bounds__(256) void k_prep(const float* __restrict__ feat,
                                              __half2* __restrict__ featH2) {
  int i = blockIdx.x * 256 + threadIdx.x;  // 20,000,000 exactly
  int a = i / 40;
  int jp = i - a * 40;
  int kk = jp * 2;
  float v0 = (kk < 75) ? feat[(size_t)a * 75 + kk] : 0.f;
  float v1 = (kk + 1 < 75) ? feat[(size_t)a * 75 + kk + 1] : 0.f;
  featH2[i] = __floats2half2_rn(v0, v1);
}

// ---------------- prep: W -> transposed fp16 [d][n=64][k=KP], k = [self || nbr] ----------------
__global__ __launch_bounds__(256) void k_prep_w(
    const float* __restrict__ Ws1, const float* __restrict__ Wn1,
    const float* __restrict__ Ws2, const float* __restrict__ Wn2,
    __half* __restrict__ W1H, __half* __restrict__ W2H) {
  int i = blockIdx.x * 256 + threadIdx.x;  // 129024 exactly
  if (i < 71680) {  // 7*64*160
    int d = i / 10240, r = i - d * 10240;
    int n = r / 160, k = r - n * 160;
    float v = 0.f;
    if (k < 75) v = Ws1[d * 4800 + k * 64 + n];
    else if (k >= 80 && k < 155 && d > 0) v = Wn1[(d - 1) * 4800 + (k - 80) * 64 + n];
    W1H[i] = __float2half(v);
  } else {
    int j = i - 71680;  // 7*64*128
    int d = j / 8192, r = j - d * 8192;
    int n = r / 128, k = r - n * 128;
    float v = 0.f;
    if (k < 64) v = Ws2[d * 4096 + k * 64 + n];
    else if (d > 0) v = Wn2[(d - 1) * 4096 + (k - 64) * 64 + n];
    W2H[j] = __float2half(v);
  }
}

// ---------------- fused graph_conv (MFMA) + tanh + bn1, fp16 in/out ----------------
// Block = 256 atoms, 4 waves; wave w owns atoms [64w,64w+64) x all 64 outputs,
// 4x4 register tile of 16x16 MFMA frags. K staged in 32-deep LDS chunks.
template<int FP, int NCH, int BSTR, int D>
__device__ __forceinline__ void gcm_run(
    const __half2* __restrict__ feat2, const int* __restrict__ adj_g,
    int abase, int na, const __half* __restrict__ WtHd,
    const float* __restrict__ bias_d,
    const float* __restrict__ bng, const float* __restrict__ bnb,
    const float* __restrict__ bnm, const float* __restrict__ bnv,
    __half* __restrict__ out,
    __half* Bt, __half* Ac, int* aidx) {
  const int KP = 2 * FP;
  const int FP2 = FP / 2;
  int tid = threadIdx.x;

  // stage W^T (coalesced global half reads; b16 LDS writes conflict-free: k fastest)
  for (int i = tid; i < 64 * KP; i += 256) {
    int n = i / KP, k = i - n * KP;
    Bt[n * BSTR + k] = WtHd[i];
  }
  if (D > 0)
    for (int i = tid; i < na * D; i += 256) aidx[i] = adj_g[i];

  int lane = tid & 63, w = tid >> 6;
  int ln = lane & 15, q = lane >> 4;

  // bn + bias per n-subtile
  float sc[4], sh[4];
  f32x4 acc[4][4];
  #pragma unroll
  for (int ns = 0; ns < 4; ns++) {
    int j = ns * 16 + ln;
    sc[ns] = bng[j] * rsqrtf(bnv[j] + 1e-3f);
    sh[ns] = bnb[j] - bnm[j] * sc[ns];
    float bj = bias_d[j];
    #pragma unroll
    for (int ms = 0; ms < 4; ms++) acc[ms][ns] = (f32x4){bj, bj, bj, bj};
  }

  __half2* Ac2 = (__half2*)Ac;
  for (int c = 0; c < NCH; c++) {
    __syncthreads();  // covers W/adj staging (c==0) and previous frag reads
    // stage A chunk: [256 atoms][16 half2], kp fastest across lanes
    #pragma unroll 4
    for (int it = 0; it < 16; it++) {
      int idx = it * 256 + tid;
      int m = idx >> 4, kp = idx & 15;
      int kk = c * 32 + 2 * kp;
      __half2 v = __floats2half2_rn(0.f, 0.f);
      if (m < na) {
        if (kk < FP) {
          v = feat2[(abase + m) * FP2 + (kk >> 1)];
        } else if (D > 0) {
          int o2 = (kk - FP) >> 1;
          const int* ar = aidx + m * D;
          v = feat2[ar[0] * FP2 + o2];
          #pragma unroll
          for (int e = 1; e < D; e++) v = __hadd2(v, feat2[ar[e] * FP2 + o2]);
        }
      }
      Ac2[m * 20 + kp] = v;
    }
    __syncthreads();

    f16x8 af[4], bf[4];
    #pragma unroll
    for (int ms = 0; ms < 4; ms++)
      af[ms] = *(const f16x8*)(Ac + (w * 64 + ms * 16 + ln) * 40 + q * 8);
    #pragma unroll
    for (int ns = 0; ns < 4; ns++)
      bf[ns] = *(const f16x8*)(Bt + (ns * 16 + ln) * BSTR + c * 32 + q * 8);
    #pragma unroll
    for (int ms = 0; ms < 4; ms++)
      #pragma unroll
      for (int ns = 0; ns < 4; ns++)
        acc[ms][ns] = __builtin_amdgcn_mfma_f32_16x16x32_f16(af[ms], bf[ns], acc[ms][ns], 0, 0, 0);
  }

  // epilogue: tanh + bn, store fp16. D layout: col(n)=lane&15, row(m)=(lane>>4)*4+reg
  #pragma unroll
  for (int ms = 0; ms < 4; ms++) {
    #pragma unroll
    for (int ns = 0; ns < 4; ns++) {
      int j = ns * 16 + ln;
      #pragma unroll
      for (int r = 0; r < 4; r++) {
        int atom = w * 64 + ms * 16 + q * 4 + r;
        if (atom < na)
          out[(size_t)(abase + atom) * 64 + j] =
              __float2half(tanh_fast(acc[ms][ns][r]) * sc[ns] + sh[ns]);
      }
    }
  }
}

template<int FP, int NCH, int BSTR>
__global__ __launch_bounds__(256, 2) void k_gcm(
    const __half2* __restrict__ feat2, AdjPtrs adjs,
    const __half* __restrict__ WtH, const float* __restrict__ bias,
    const float* __restrict__ bng, const float* __restrict__ bnb,
    const float* __restrict__ bnm, const float* __restrict__ bnv,
    __half* __restrict__ out) {
  __shared__ __align__(16) __half Bt[64 * BSTR];
  __shared__ __align__(16) __half Ac[256 * 40];
  __shared__ int aidx[256 * 6];

  int bid = blockIdx.x;
  int d, off, end, bloc;
  if      (bid < 79)   { d = 0; bloc = bid;        off = 0;      end = 20000;  }
  else if (bid < 392)  { d = 1; bloc = bid - 79;   off = 20000;  end = 100000; }
  else if (bid < 978)  { d = 2; bloc = bid - 392;  off = 100000; end = 250000; }
  else if (bid < 1564) { d = 3; bloc = bid - 978;  off = 250000; end = 400000; }
  else if (bid < 1857) { d = 4; bloc = bid - 1564; off = 400000; end = 475000; }
  else if (bid < 1936) { d = 5; bloc = bid - 1857; off = 475000; end = 495000; }
  else                 { d = 6; bloc = bid - 1936; off = 495000; end = 500000; }
  int abase = off + bloc * 256;
  int na = min(256, end - abase);
  const int* adj_g = (d > 0) ? adjs.p[d - 1] + (abase - off) * d : (const int*)0;
  const __half* WtHd = WtH + d * 64 * 2 * FP;
  const float* bias_d = bias + d * 64;

  switch (d) {
    case 0: gcm_run<FP, NCH, BSTR, 0>(feat2, adj_g, abase, na, WtHd, bias_d, bng, bnb, bnm, bnv, out, Bt, Ac, aidx); break;
    case 1: gcm_run<FP, NCH, BSTR, 1>(feat2, adj_g, abase, na, WtHd, bias_d, bng, bnb, bnm, bnv, out, Bt, Ac, aidx); break;
    case 2: gcm_run<FP, NCH, BSTR, 2>(feat2, adj_g, abase, na, WtHd, bias_d, bng, bnb, bnm, bnv, out, Bt, Ac, aidx); break;
    case 3: gcm_run<FP, NCH, BSTR, 3>(feat2, adj_g, abase, na, WtHd, bias_d, bng, bnb, bnm, bnv, out, Bt, Ac, aidx); break;
    case 4: gcm_run<FP, NCH, BSTR, 4>(feat2, adj_g, abase, na, WtHd, bias_d, bng, bnb, bnm, bnv, out, Bt, Ac, aidx); break;
    case 5: gcm_run<FP, NCH, BSTR, 5>(feat2, adj_g, abase, na, WtHd, bias_d, bng, bnb, bnm, bnv, out, Bt, Ac, aidx); break;
    default: gcm_run<FP, NCH, BSTR, 6>(feat2, adj_g, abase, na, WtHd, bias_d, bng, bnb, bnm, bnv, out, Bt, Ac, aidx); break;
  }
}

// ---------------- graph_pool fp16: out = max(self, neighbors) ----------------
template<int D>
__device__ __forceinline__ void pool_h_acc(const __half2* __restrict__ in2,
                                           const int* __restrict__ ad, int g2,
                                           float2& f0, float2& f1) {
  #pragma unroll
  for (int e = 0; e < D; e++) {
    int nb = ad[e];
    float2 h0 = __half22float2(in2[nb * 32 + g2]);
    float2 h1 = __half22float2(in2[nb * 32 + g2 + 1]);
    f0.x = fmaxf(f0.x, h0.x); f0.y = fmaxf(f0.y, h0.y);
    f1.x = fmaxf(f1.x, h1.x); f1.y = fmaxf(f1.y, h1.y);
  }
}

__global__ __launch_bounds__(256) void k_pool_h(const __half2* __restrict__ in2, AdjPtrs adjs,
                                                __half2* __restrict__ out2) {
  int t = blockIdx.x * 256 + threadIdx.x;  // 8,000,000 exactly
  int atom = t >> 4, g2 = (t & 15) * 2;
  int d, off;
  if      (atom < 20000)  { d = 0; off = 0;      }
  else if (atom < 100000) { d = 1; off = 20000;  }
  else if (atom < 250000) { d = 2; off = 100000; }
  else if (atom < 400000) { d = 3; off = 250000; }
  else if (atom < 475000) { d = 4; off = 400000; }
  else if (atom < 495000) { d = 5; off = 475000; }
  else                    { d = 6; off = 495000; }
  int base = atom * 32 + g2;
  float2 f0 = __half22float2(in2[base]);
  float2 f1 = __half22float2(in2[base + 1]);
  if (d > 0) {
    const int* ad = adjs.p[d - 1] + (atom - off) * d;
    switch (d) {
      case 1: pool_h_acc<1>(in2, ad, g2, f0, f1); break;
      case 2: pool_h_acc<2>(in2, ad, g2, f0, f1); break;
      case 3: pool_h_acc<3>(in2, ad, g2, f0, f1); break;
      case 4: pool_h_acc<4>(in2, ad, g2, f0, f1); break;
      case 5: pool_h_acc<5>(in2, ad, g2, f0, f1); break;
      default: pool_h_acc<6>(in2, ad, g2, f0, f1); break;
    }
  }
  out2[base] = __floats2half2_rn(f0.x, f0.y);
  out2[base + 1] = __floats2half2_rn(f1.x, f1.y);
}

// ---------------- fused dense1 + tanh + bn3 + segment sum/max + tanh ----------------
__global__ __launch_bounds__(128) void k_gather_dense1(
    const __half* __restrict__ h, const int* __restrict__ list,
    const int* __restrict__ start, const int* __restrict__ hist,
    const float* __restrict__ W, const float* __restrict__ bvec,
    const float* __restrict__ g3, const float* __restrict__ b3,
    const float* __restrict__ m3, const float* __restrict__ v3,
    float* __restrict__ g) {
  __shared__ float rows[8 * 64];
  int b = blockIdx.x, tid = threadIdx.x;

  float Wc[64];
  #pragma unroll
  for (int k = 0; k < 64; k++) Wc[k] = W[k * 128 + tid];
  float scj = g3[tid] * rsqrtf(v3[tid] + 1e-3f);
  float shj = b3[tid] - m3[tid] * scj;
  float bj  = bvec[tid];

  float s = 0.f, m = -INFINITY;
  int stt = start[b], cnt = hist[b];

  for (int t0 = 0; t0 < cnt; t0 += 8) {
    int nr = min(8, cnt - t0);
    __syncthreads();
    if (tid < nr * 16) {
      int r = tid >> 4, c = tid & 15;
      int a = list[stt + t0 + r];
      const __half2* hp = (const __half2*)h + (size_t)a * 32 + c * 2;
      float2 f0 = __half22float2(hp[0]);
      float2 f1 = __half22float2(hp[1]);
      *(float4*)(rows + r * 64 + c * 4) = make_float4(f0.x, f0.y, f1.x, f1.y);
    }
    __syncthreads();
    for (int r = 0; r < nr; r++) {
      const float* x = rows + r * 64;
      float a0 = bj, a1 = 0.f, a2 = 0.f, a3 = 0.f;
      #pragma unroll
      for (int k = 0; k < 64; k += 4) {
        float4 x4 = *(const float4*)(x + k);
        a0 += x4.x * Wc[k];
        a1 += x4.y * Wc[k + 1];
        a2 += x4.z * Wc[k + 2];
        a3 += x4.w * Wc[k + 3];
      }
      float v = tanh_fast((a0 + a1) + (a2 + a3));
      v = v * scj + shj;
      s += v;
      m = fmaxf(m, v);
    }
  }
  g[b * 256 + tid]       = tanh_fast(s);
  g[b * 256 + 128 + tid] = tanh_fast(m);
}

// ---------------- dense2 -> sigmoid -> dense3 ----------------
__global__ __launch_bounds__(64) void k_dense23(
    const float* __restrict__ g, const float* __restrict__ W2,
    const float* __restrict__ b2, const float* __restrict__ W3,
    const float* __restrict__ b3, float* __restrict__ out) {
  __shared__ float gr[256];
  int b = blockIdx.x, j = threadIdx.x;
  ((float4*)gr)[j] = ((const float4*)(g + b * 256))[j];
  __syncthreads();
  float acc = b2[j];
  #pragma unroll 8
  for (int k = 0; k < 256; k++) acc += gr[k] * W2[k * 64 + j];
  float sg = 1.f / (1.f + expf(-acc));
  float p = sg * W3[j];
  #pragma unroll
  for (int off = 32; off >= 1; off >>= 1) p += __shfl_xor(p, off);
  if (j == 0) out[b] = p + b3[0];
}

// ---------------- launch ----------------
extern "C" void kernel_launch(void* const* d_in, const int* in_sizes, int n_in,
                              void* d_out, int out_size, void* d_ws, size_t ws_size,
                              hipStream_t stream) {
  const float* feat = (const float*)d_in[0];
  const int*   mem  = (const int*)d_in[1];
  AdjPtrs adjs;
  for (int i = 0; i < 6; i++) adjs.p[i] = (const int*)d_in[2 + i];
  const float* gc1_Wn = (const float*)d_in[8];
  const float* gc1_Ws = (const float*)d_in[9];
  const float* gc1_b  = (const float*)d_in[10];
  const float* gc2_Wn = (const float*)d_in[11];
  const float* gc2_Ws = (const float*)d_in[12];
  const float* gc2_b  = (const float*)d_in[13];
  const float* bn1g = (const float*)d_in[14];
  const float* bn1b = (const float*)d_in[15];
  const float* bn1m = (const float*)d_in[16];
  const float* bn1v = (const float*)d_in[17];
  const float* bn3g = (const float*)d_in[18];
  const float* bn3b = (const float*)d_in[19];
  const float* bn3m = (const float*)d_in[20];
  const float* bn3v = (const float*)d_in[21];
  const float* d1W = (const float*)d_in[22];
  const float* d1b = (const float*)d_in[23];
  const float* d2W = (const float*)d_in[24];
  const float* d2b = (const float*)d_in[25];
  const float* d3W = (const float*)d_in[26];
  const float* d3b = (const float*)d_in[27];
  float* out = (float*)d_out;

  // workspace layout (bytes):
  // featH @0 (80 MB) | hA @80e6 (64 MB) | hB @144e6 (64 MB)
  // gc2 out (hC) reuses featH region @0; pool2 out (hD) reuses hA region @80e6
  char* w = (char*)d_ws;
  __half* featH = (__half*)(w);
  __half* hA    = (__half*)(w + 80000000LL);
  __half* hB    = (__half*)(w + 144000000LL);
  __half* hC    = (__half*)(w);              // gc2 out (featH dead)
  __half* hD    = (__half*)(w + 80000000LL); // pool2 out (hA dead)
  __half* W1H   = (__half*)(w + 210000000LL);  // 143,360 B
  __half* W2H   = (__half*)(w + 210200000LL);  // 114,688 B
  float*  g     = (float*)(w + 210400000LL);   // 1 MB
  int* hist     = (int*)(w + 211600000LL);
  int* start    = (int*)(w + 211604096LL);
  int* cursor   = (int*)(w + 211608192LL);
  int* list     = (int*)(w + 211612288LL);     // 2 MB

  // membership counting sort
  k_zero_hist<<<4, 256, 0, stream>>>(hist);
  k_hist<<<512, 256, 0, stream>>>(mem, hist);
  k_scan<<<1, 1024, 0, stream>>>(hist, start, cursor);
  k_scatter<<<1954, 256, 0, stream>>>(mem, cursor, list);

  // prep
  k_prep<<<78125, 256, 0, stream>>>(feat, (__half2*)featH);
  k_prep_w<<<504, 256, 0, stream>>>(gc1_Ws, gc1_Wn, gc2_Ws, gc2_Wn, W1H, W2H);

  // main pipeline
  k_gcm<80, 5, 168><<<1956, 256, 0, stream>>>((const __half2*)featH, adjs, W1H, gc1_b,
                                              bn1g, bn1b, bn1m, bn1v, hA);
  k_pool_h<<<31250, 256, 0, stream>>>((const __half2*)hA, adjs, (__half2*)hB);
  k_gcm<64, 4, 136><<<1956, 256, 0, stream>>>((const __half2*)hB, adjs, W2H, gc2_b,
                                              bn1g, bn1b, bn1m, bn1v, hC);
  k_pool_h<<<31250, 256, 0, stream>>>((const __half2*)hC, adjs, (__half2*)hD);
  k_gather_dense1<<<1024, 128, 0, stream>>>(hD, list, start, hist, d1W, d1b,
                                            bn3g, bn3b, bn3m, bn3v, g);
  k_dense23<<<1024, 64, 0, stream>>>(g, d2W, d2b, d3W, d3b, out);
}

// Round 4
// 911.668 us; speedup vs baseline: 2.2949x; 1.2199x over previous
//
#include <hip/hip_runtime.h>
#include <hip/hip_fp16.h>
#include <math.h>

// DEG_COUNTS = [20000, 80000, 150000, 150000, 75000, 20000, 5000]
// OFF        = [0, 20000, 100000, 250000, 400000, 475000, 495000, 500000]
// N_ATOMS = 500000, BATCH = 1024, F_IN = 75

struct AdjPtrs { const int* p[6]; };

typedef _Float16 f16x8 __attribute__((ext_vector_type(8)));
typedef float f32x4 __attribute__((ext_vector_type(4)));

__device__ __forceinline__ float tanh_fast(float x) {
  float ax = fabsf(x);
  float r = __expf(-2.f * ax);             // r in (0,1], never inf
  float t = 1.f - 2.f * r * __builtin_amdgcn_rcpf(1.f + r);
  return copysignf(t, x);
}

// ---------------- membership counting sort ----------------
__global__ __launch_bounds__(256) void k_zero_hist(int* __restrict__ hist) {
  int i = blockIdx.x * 256 + threadIdx.x;
  if (i < 1024) hist[i] = 0;
}

__global__ __launch_bounds__(256) void k_hist(const int* __restrict__ mem, int* __restrict__ hist) {
  __shared__ int lh[1024];
  int tid = threadIdx.x;
  for (int i = tid; i < 1024; i += 256) lh[i] = 0;
  __syncthreads();
  int stride = gridDim.x * 256;
  for (int i = blockIdx.x * 256 + tid; i < 500000; i += stride)
    atomicAdd(&lh[mem[i]], 1);
  __syncthreads();
  for (int i = tid; i < 1024; i += 256) {
    int v = lh[i];
    if (v) atomicAdd(&hist[i], v);
  }
}

__global__ __launch_bounds__(1024) void k_scan(const int* __restrict__ hist,
                                               int* __restrict__ start,
                                               int* __restrict__ cursor) {
  __shared__ int sc[1024];
  int t = threadIdx.x;
  int h = hist[t];
  sc[t] = h;
  __syncthreads();
  for (int off = 1; off < 1024; off <<= 1) {
    int v = (t >= off) ? sc[t - off] : 0;
    __syncthreads();
    sc[t] += v;
    __syncthreads();
  }
  int ex = sc[t] - h;
  start[t] = ex;
  cursor[t] = ex;
}

__global__ __launch_bounds__(256) void k_scatter(const int* __restrict__ mem,
                                                 int* __restrict__ cursor,
                                                 int* __restrict__ list) {
  int i = blockIdx.x * 256 + threadIdx.x;
  if (i < 500000) {
    int pos = atomicAdd(&cursor[mem[i]], 1);
    list[pos] = i;
  }
}

// ---------------- prep: feat fp32[500k x 75] -> fp16 padded [500k x 80] ----------------
__global__ __launch_bounds__(256) void k_prep(const float* __restrict__ feat,
                                              __half2* __restrict__ featH2) {
  int i = blockIdx.x * 256 + threadIdx.x;  // 20,000,000 exactly
  int a = i / 40;
  int jp = i - a * 40;
  int kk = jp * 2;
  float v0 = (kk < 75) ? feat[(size_t)a * 75 + kk] : 0.f;
  float v1 = (kk + 1 < 75) ? feat[(size_t)a * 75 + kk + 1] : 0.f;
  featH2[i] = __floats2half2_rn(v0, v1);
}

// ---------------- prep: W -> transposed fp16 [d][n=64][k=KP], k = [self || nbr] ----------------
__global__ __launch_bounds__(256) void k_prep_w(
    const float* __restrict__ Ws1, const float* __restrict__ Wn1,
    const float* __restrict__ Ws2, const float* __restrict__ Wn2,
    __half* __restrict__ W1H, __half* __restrict__ W2H) {
  int i = blockIdx.x * 256 + threadIdx.x;  // 129024 exactly
  if (i < 71680) {  // 7*64*160
    int d = i / 10240, r = i - d * 10240;
    int n = r / 160, k = r - n * 160;
    float v = 0.f;
    if (k < 75) v = Ws1[d * 4800 + k * 64 + n];
    else if (k >= 80 && k < 155 && d > 0) v = Wn1[(d - 1) * 4800 + (k - 80) * 64 + n];
    W1H[i] = __float2half(v);
  } else {
    int j = i - 71680;  // 7*64*128
    int d = j / 8192, r = j - d * 8192;
    int n = r / 128, k = r - n * 128;
    float v = 0.f;
    if (k < 64) v = Ws2[d * 4096 + k * 64 + n];
    else if (d > 0) v = Wn2[(d - 1) * 4096 + (k - 64) * 64 + n];
    W2H[j] = __float2half(v);
  }
}

// ---------------- prep: d1_W (64x128 fp32) -> hi/lo fp16 [2][128][64] ----------------
__global__ __launch_bounds__(256) void k_prep_d1(const float* __restrict__ W,
                                                 __half* __restrict__ D1H) {
  int i = blockIdx.x * 256 + threadIdx.x;  // 8192 exactly
  int n = i >> 6, k = i & 63;
  float v = W[k * 128 + n];
  __half hi = __float2half(v);
  D1H[i] = hi;
  D1H[8192 + i] = __float2half(v - __half2float(hi));
}

// ---------------- fused graph_conv (MFMA) + tanh + bn1, fp16 in/out ----------------
template<int FP, int NCH, int BSTR, int D>
__device__ __forceinline__ void gcm_run(
    const __half2* __restrict__ feat2, const int* __restrict__ adj_g,
    int abase, int na, const __half* __restrict__ WtHd,
    const float* __restrict__ bias_d,
    const float* __restrict__ bng, const float* __restrict__ bnb,
    const float* __restrict__ bnm, const float* __restrict__ bnv,
    __half* __restrict__ out,
    __half* Bt, __half* Ac, int* aidx) {
  const int KP = 2 * FP;
  const int FP2 = FP / 2;
  int tid = threadIdx.x;

  for (int i = tid; i < 64 * KP; i += 256) {
    int n = i / KP, k = i - n * KP;
    Bt[n * BSTR + k] = WtHd[i];
  }
  if (D > 0)
    for (int i = tid; i < na * D; i += 256) aidx[i] = adj_g[i];

  int lane = tid & 63, w = tid >> 6;
  int ln = lane & 15, q = lane >> 4;

  float sc[4], sh[4];
  f32x4 acc[4][4];
  #pragma unroll
  for (int ns = 0; ns < 4; ns++) {
    int j = ns * 16 + ln;
    sc[ns] = bng[j] * rsqrtf(bnv[j] + 1e-3f);
    sh[ns] = bnb[j] - bnm[j] * sc[ns];
    float bj = bias_d[j];
    #pragma unroll
    for (int ms = 0; ms < 4; ms++) acc[ms][ns] = (f32x4){bj, bj, bj, bj};
  }

  __half2* Ac2 = (__half2*)Ac;
  for (int c = 0; c < NCH; c++) {
    __syncthreads();
    #pragma unroll 4
    for (int it = 0; it < 16; it++) {
      int idx = it * 256 + tid;
      int m = idx >> 4, kp = idx & 15;
      int kk = c * 32 + 2 * kp;
      __half2 v = __floats2half2_rn(0.f, 0.f);
      if (m < na) {
        if (kk < FP) {
          v = feat2[(abase + m) * FP2 + (kk >> 1)];
        } else if (D > 0) {
          int o2 = (kk - FP) >> 1;
          const int* ar = aidx + m * D;
          v = feat2[ar[0] * FP2 + o2];
          #pragma unroll
          for (int e = 1; e < D; e++) v = __hadd2(v, feat2[ar[e] * FP2 + o2]);
        }
      }
      Ac2[m * 20 + kp] = v;
    }
    __syncthreads();

    f16x8 af[4], bf[4];
    #pragma unroll
    for (int ms = 0; ms < 4; ms++)
      af[ms] = *(const f16x8*)(Ac + (w * 64 + ms * 16 + ln) * 40 + q * 8);
    #pragma unroll
    for (int ns = 0; ns < 4; ns++)
      bf[ns] = *(const f16x8*)(Bt + (ns * 16 + ln) * BSTR + c * 32 + q * 8);
    #pragma unroll
    for (int ms = 0; ms < 4; ms++)
      #pragma unroll
      for (int ns = 0; ns < 4; ns++)
        acc[ms][ns] = __builtin_amdgcn_mfma_f32_16x16x32_f16(af[ms], bf[ns], acc[ms][ns], 0, 0, 0);
  }

  #pragma unroll
  for (int ms = 0; ms < 4; ms++) {
    #pragma unroll
    for (int ns = 0; ns < 4; ns++) {
      int j = ns * 16 + ln;
      #pragma unroll
      for (int r = 0; r < 4; r++) {
        int atom = w * 64 + ms * 16 + q * 4 + r;
        if (atom < na)
          out[(size_t)(abase + atom) * 64 + j] =
              __float2half(tanh_fast(acc[ms][ns][r]) * sc[ns] + sh[ns]);
      }
    }
  }
}

template<int FP, int NCH, int BSTR>
__global__ __launch_bounds__(256, 2) void k_gcm(
    const __half2* __restrict__ feat2, AdjPtrs adjs,
    const __half* __restrict__ WtH, const float* __restrict__ bias,
    const float* __restrict__ bng, const float* __restrict__ bnb,
    const float* __restrict__ bnm, const float* __restrict__ bnv,
    __half* __restrict__ out) {
  __shared__ __align__(16) __half Bt[64 * BSTR];
  __shared__ __align__(16) __half Ac[256 * 40];
  __shared__ int aidx[256 * 6];

  int bid = blockIdx.x;
  int d, off, end, bloc;
  if      (bid < 79)   { d = 0; bloc = bid;        off = 0;      end = 20000;  }
  else if (bid < 392)  { d = 1; bloc = bid - 79;   off = 20000;  end = 100000; }
  else if (bid < 978)  { d = 2; bloc = bid - 392;  off = 100000; end = 250000; }
  else if (bid < 1564) { d = 3; bloc = bid - 978;  off = 250000; end = 400000; }
  else if (bid < 1857) { d = 4; bloc = bid - 1564; off = 400000; end = 475000; }
  else if (bid < 1936) { d = 5; bloc = bid - 1857; off = 475000; end = 495000; }
  else                 { d = 6; bloc = bid - 1936; off = 495000; end = 500000; }
  int abase = off + bloc * 256;
  int na = min(256, end - abase);
  const int* adj_g = (d > 0) ? adjs.p[d - 1] + (abase - off) * d : (const int*)0;
  const __half* WtHd = WtH + d * 64 * 2 * FP;
  const float* bias_d = bias + d * 64;

  switch (d) {
    case 0: gcm_run<FP, NCH, BSTR, 0>(feat2, adj_g, abase, na, WtHd, bias_d, bng, bnb, bnm, bnv, out, Bt, Ac, aidx); break;
    case 1: gcm_run<FP, NCH, BSTR, 1>(feat2, adj_g, abase, na, WtHd, bias_d, bng, bnb, bnm, bnv, out, Bt, Ac, aidx); break;
    case 2: gcm_run<FP, NCH, BSTR, 2>(feat2, adj_g, abase, na, WtHd, bias_d, bng, bnb, bnm, bnv, out, Bt, Ac, aidx); break;
    case 3: gcm_run<FP, NCH, BSTR, 3>(feat2, adj_g, abase, na, WtHd, bias_d, bng, bnb, bnm, bnv, out, Bt, Ac, aidx); break;
    case 4: gcm_run<FP, NCH, BSTR, 4>(feat2, adj_g, abase, na, WtHd, bias_d, bng, bnb, bnm, bnv, out, Bt, Ac, aidx); break;
    case 5: gcm_run<FP, NCH, BSTR, 5>(feat2, adj_g, abase, na, WtHd, bias_d, bng, bnb, bnm, bnv, out, Bt, Ac, aidx); break;
    default: gcm_run<FP, NCH, BSTR, 6>(feat2, adj_g, abase, na, WtHd, bias_d, bng, bnb, bnm, bnv, out, Bt, Ac, aidx); break;
  }
}

// ---------------- graph_pool fp16 ----------------
template<int D>
__device__ __forceinline__ void pool_h_acc(const __half2* __restrict__ in2,
                                           const int* __restrict__ ad, int g2,
                                           float2& f0, float2& f1) {
  #pragma unroll
  for (int e = 0; e < D; e++) {
    int nb = ad[e];
    float2 h0 = __half22float2(in2[nb * 32 + g2]);
    float2 h1 = __half22float2(in2[nb * 32 + g2 + 1]);
    f0.x = fmaxf(f0.x, h0.x); f0.y = fmaxf(f0.y, h0.y);
    f1.x = fmaxf(f1.x, h1.x); f1.y = fmaxf(f1.y, h1.y);
  }
}

__global__ __launch_bounds__(256) void k_pool_h(const __half2* __restrict__ in2, AdjPtrs adjs,
                                                __half2* __restrict__ out2) {
  int t = blockIdx.x * 256 + threadIdx.x;  // 8,000,000 exactly
  int atom = t >> 4, g2 = (t & 15) * 2;
  int d, off;
  if      (atom < 20000)  { d = 0; off = 0;      }
  else if (atom < 100000) { d = 1; off = 20000;  }
  else if (atom < 250000) { d = 2; off = 100000; }
  else if (atom < 400000) { d = 3; off = 250000; }
  else if (atom < 475000) { d = 4; off = 400000; }
  else if (atom < 495000) { d = 5; off = 475000; }
  else                    { d = 6; off = 495000; }
  int base = atom * 32 + g2;
  float2 f0 = __half22float2(in2[base]);
  float2 f1 = __half22float2(in2[base + 1]);
  if (d > 0) {
    const int* ad = adjs.p[d - 1] + (atom - off) * d;
    switch (d) {
      case 1: pool_h_acc<1>(in2, ad, g2, f0, f1); break;
      case 2: pool_h_acc<2>(in2, ad, g2, f0, f1); break;
      case 3: pool_h_acc<3>(in2, ad, g2, f0, f1); break;
      case 4: pool_h_acc<4>(in2, ad, g2, f0, f1); break;
      case 5: pool_h_acc<5>(in2, ad, g2, f0, f1); break;
      default: pool_h_acc<6>(in2, ad, g2, f0, f1); break;
    }
  }
  out2[base] = __floats2half2_rn(f0.x, f0.y);
  out2[base + 1] = __floats2half2_rn(f1.x, f1.y);
}

// ---------------- fused dense1(MFMA, hi/lo W) + tanh + bn3 + segment sum/max + tanh ----
// One block (256 thr, 4 waves) per batch element. Wave w: cols w*32..w*32+31 (2 n-frags),
// all 64 rows of each chunk (4 m-frags). Sum/max accumulated in fp32 registers.
__global__ __launch_bounds__(256, 3) void k_dense1f(
    const __half2* __restrict__ hD2, const int* __restrict__ list,
    const int* __restrict__ start, const int* __restrict__ hist,
    const __half* __restrict__ D1H, const float* __restrict__ d1b,
    const float* __restrict__ g3, const float* __restrict__ b3,
    const float* __restrict__ m3, const float* __restrict__ v3,
    float* __restrict__ g) {
  __shared__ __align__(16) __half Bt[2][128 * 72];
  __shared__ __align__(16) __half Ac[64 * 72];
  int b = blockIdx.x, tid = threadIdx.x;
  int stt = start[b], cnt = hist[b];

  for (int i = tid; i < 8192; i += 256) {
    int n = i >> 6, k = i & 63;
    Bt[0][n * 72 + k] = D1H[i];
    Bt[1][n * 72 + k] = D1H[8192 + i];
  }

  int lane = tid & 63, w = tid >> 6;
  int ln = lane & 15, q = lane >> 4;

  float bj[2], sc[2], sh[2];
  #pragma unroll
  for (int nf = 0; nf < 2; nf++) {
    int col = w * 32 + nf * 16 + ln;
    bj[nf] = d1b[col];
    sc[nf] = g3[col] * rsqrtf(v3[col] + 1e-3f);
    sh[nf] = b3[col] - m3[col] * sc[nf];
  }

  float sum[2] = {0.f, 0.f};
  float mx[2] = {-INFINITY, -INFINITY};

  for (int cb = 0; cb < cnt; cb += 64) {
    int nr = min(64, cnt - cb);
    __syncthreads();  // covers W staging (1st iter) + prior Ac readers
    {
      int r = tid >> 2;
      #pragma unroll
      for (int it = 0; it < 2; it++) {
        int sg = (tid & 3) + it * 4;  // 8-half (16 B) segment
        __half2* dst = (__half2*)(Ac + r * 72 + sg * 8);
        if (r < nr) {
          int a = list[stt + cb + r];
          const __half2* src = hD2 + (size_t)a * 32 + sg * 4;
          __half2 v0 = src[0], v1 = src[1], v2 = src[2], v3h = src[3];
          dst[0] = v0; dst[1] = v1; dst[2] = v2; dst[3] = v3h;
        } else {
          __half2 z = __floats2half2_rn(0.f, 0.f);
          dst[0] = z; dst[1] = z; dst[2] = z; dst[3] = z;
        }
      }
    }
    __syncthreads();

    f32x4 acc[4][2];
    #pragma unroll
    for (int mf = 0; mf < 4; mf++)
      #pragma unroll
      for (int nf = 0; nf < 2; nf++) acc[mf][nf] = (f32x4){bj[nf], bj[nf], bj[nf], bj[nf]};

    #pragma unroll
    for (int hl = 1; hl >= 0; hl--) {
      #pragma unroll
      for (int ks = 0; ks < 2; ks++) {
        f16x8 af[4], bf[2];
        #pragma unroll
        for (int mf = 0; mf < 4; mf++)
          af[mf] = *(const f16x8*)(Ac + (mf * 16 + ln) * 72 + ks * 32 + q * 8);
        #pragma unroll
        for (int nf = 0; nf < 2; nf++)
          bf[nf] = *(const f16x8*)(&Bt[hl][(w * 32 + nf * 16 + ln) * 72 + ks * 32 + q * 8]);
        #pragma unroll
        for (int mf = 0; mf < 4; mf++)
          #pragma unroll
          for (int nf = 0; nf < 2; nf++)
            acc[mf][nf] = __builtin_amdgcn_mfma_f32_16x16x32_f16(af[mf], bf[nf], acc[mf][nf], 0, 0, 0);
      }
    }

    #pragma unroll
    for (int mf = 0; mf < 4; mf++) {
      #pragma unroll
      for (int nf = 0; nf < 2; nf++) {
        #pragma unroll
        for (int r = 0; r < 4; r++) {
          int row = mf * 16 + q * 4 + r;
          if (row < nr) {
            float v = tanh_fast(acc[mf][nf][r]) * sc[nf] + sh[nf];
            sum[nf] += v;
            mx[nf] = fmaxf(mx[nf], v);
          }
        }
      }
    }
  }

  #pragma unroll
  for (int nf = 0; nf < 2; nf++) {
    sum[nf] += __shfl_xor(sum[nf], 16);
    sum[nf] += __shfl_xor(sum[nf], 32);
    mx[nf] = fmaxf(mx[nf], __shfl_xor(mx[nf], 16));
    mx[nf] = fmaxf(mx[nf], __shfl_xor(mx[nf], 32));
  }
  if (q == 0) {
    #pragma unroll
    for (int nf = 0; nf < 2; nf++) {
      int col = w * 32 + nf * 16 + ln;
      g[b * 256 + col] = tanh_fast(sum[nf]);
      g[b * 256 + 128 + col] = tanh_fast(mx[nf]);
    }
  }
}

// ---------------- dense2 -> sigmoid -> dense3 ----------------
__global__ __launch_bounds__(64) void k_dense23(
    const float* __restrict__ g, const float* __restrict__ W2,
    const float* __restrict__ b2, const float* __restrict__ W3,
    const float* __restrict__ b3, float* __restrict__ out) {
  __shared__ float gr[256];
  int b = blockIdx.x, j = threadIdx.x;
  ((float4*)gr)[j] = ((const float4*)(g + b * 256))[j];
  __syncthreads();
  float acc = b2[j];
  #pragma unroll 8
  for (int k = 0; k < 256; k++) acc += gr[k] * W2[k * 64 + j];
  float sg = 1.f / (1.f + expf(-acc));
  float p = sg * W3[j];
  #pragma unroll
  for (int off = 32; off >= 1; off >>= 1) p += __shfl_xor(p, off);
  if (j == 0) out[b] = p + b3[0];
}

// ---------------- launch ----------------
extern "C" void kernel_launch(void* const* d_in, const int* in_sizes, int n_in,
                              void* d_out, int out_size, void* d_ws, size_t ws_size,
                              hipStream_t stream) {
  const float* feat = (const float*)d_in[0];
  const int*   mem  = (const int*)d_in[1];
  AdjPtrs adjs;
  for (int i = 0; i < 6; i++) adjs.p[i] = (const int*)d_in[2 + i];
  const float* gc1_Wn = (const float*)d_in[8];
  const float* gc1_Ws = (const float*)d_in[9];
  const float* gc1_b  = (const float*)d_in[10];
  const float* gc2_Wn = (const float*)d_in[11];
  const float* gc2_Ws = (const float*)d_in[12];
  const float* gc2_b  = (const float*)d_in[13];
  const float* bn1g = (const float*)d_in[14];
  const float* bn1b = (const float*)d_in[15];
  const float* bn1m = (const float*)d_in[16];
  const float* bn1v = (const float*)d_in[17];
  const float* bn3g = (const float*)d_in[18];
  const float* bn3b = (const float*)d_in[19];
  const float* bn3m = (const float*)d_in[20];
  const float* bn3v = (const float*)d_in[21];
  const float* d1W = (const float*)d_in[22];
  const float* d1b = (const float*)d_in[23];
  const float* d2W = (const float*)d_in[24];
  const float* d2b = (const float*)d_in[25];
  const float* d3W = (const float*)d_in[26];
  const float* d3b = (const float*)d_in[27];
  float* out = (float*)d_out;

  char* w = (char*)d_ws;
  __half* featH = (__half*)(w);
  __half* hA    = (__half*)(w + 80000000LL);
  __half* hB    = (__half*)(w + 144000000LL);
  __half* hC    = (__half*)(w);              // gc2 out (featH dead)
  __half* hD    = (__half*)(w + 80000000LL); // pool2 out (hA dead)
  __half* W1H   = (__half*)(w + 210000000LL);
  __half* W2H   = (__half*)(w + 210200000LL);
  __half* D1H   = (__half*)(w + 210330000LL);  // 32 KB hi/lo
  float*  g     = (float*)(w + 210400000LL);   // 1 MB
  int* hist     = (int*)(w + 211600000LL);
  int* start    = (int*)(w + 211604096LL);
  int* cursor   = (int*)(w + 211608192LL);
  int* list     = (int*)(w + 211612288LL);     // 2 MB

  // membership counting sort
  k_zero_hist<<<4, 256, 0, stream>>>(hist);
  k_hist<<<512, 256, 0, stream>>>(mem, hist);
  k_scan<<<1, 1024, 0, stream>>>(hist, start, cursor);
  k_scatter<<<1954, 256, 0, stream>>>(mem, cursor, list);

  // prep
  k_prep<<<78125, 256, 0, stream>>>(feat, (__half2*)featH);
  k_prep_w<<<504, 256, 0, stream>>>(gc1_Ws, gc1_Wn, gc2_Ws, gc2_Wn, W1H, W2H);
  k_prep_d1<<<32, 256, 0, stream>>>(d1W, D1H);

  // main pipeline
  k_gcm<80, 5, 168><<<1956, 256, 0, stream>>>((const __half2*)featH, adjs, W1H, gc1_b,
                                              bn1g, bn1b, bn1m, bn1v, hA);
  k_pool_h<<<31250, 256, 0, stream>>>((const __half2*)hA, adjs, (__half2*)hB);
  k_gcm<64, 4, 136><<<1956, 256, 0, stream>>>((const __half2*)hB, adjs, W2H, gc2_b,
                                              bn1g, bn1b, bn1m, bn1v, hC);
  k_pool_h<<<31250, 256, 0, stream>>>((const __half2*)hC, adjs, (__half2*)hD);
  k_dense1f<<<1024, 256, 0, stream>>>((const __half2*)hD, list, start, hist, D1H, d1b,
                                      bn3g, bn3b, bn3m, bn3v, g);
  k_dense23<<<1024, 64, 0, stream>>>(g, d2W, d2b, d3W, d3b, out);
}

// Round 6
// 765.137 us; speedup vs baseline: 2.7344x; 1.1915x over previous
//
#include <hip/hip_runtime.h>
#include <hip/hip_fp16.h>
#include <math.h>

// DEG_COUNTS = [20000, 80000, 150000, 150000, 75000, 20000, 5000]
// OFF        = [0, 20000, 100000, 250000, 400000, 475000, 495000, 500000]
// N_ATOMS = 500000, BATCH = 1024, F_IN = 75

struct AdjPtrs { const int* p[6]; };

typedef _Float16 f16x8 __attribute__((ext_vector_type(8)));
typedef float f32x4 __attribute__((ext_vector_type(4)));

__device__ __forceinline__ float tanh_fast(float x) {
  float ax = fabsf(x);
  float r = __expf(-2.f * ax);             // r in (0,1], never inf
  float t = 1.f - 2.f * r * __builtin_amdgcn_rcpf(1.f + r);
  return copysignf(t, x);
}

__device__ __forceinline__ f16x8 max8(f16x8 a, f16x8 b) {
  #pragma unroll
  for (int i = 0; i < 8; i++) a[i] = (a[i] > b[i]) ? a[i] : b[i];  // -> v_pk_max_f16
  return a;
}

// ---------------- membership counting sort ----------------
__global__ __launch_bounds__(256) void k_zero_hist(int* __restrict__ hist) {
  int i = blockIdx.x * 256 + threadIdx.x;
  if (i < 1024) hist[i] = 0;
}

__global__ __launch_bounds__(256) void k_hist(const int* __restrict__ mem, int* __restrict__ hist) {
  __shared__ int lh[1024];
  int tid = threadIdx.x;
  for (int i = tid; i < 1024; i += 256) lh[i] = 0;
  __syncthreads();
  int stride = gridDim.x * 256;
  for (int i = blockIdx.x * 256 + tid; i < 500000; i += stride)
    atomicAdd(&lh[mem[i]], 1);
  __syncthreads();
  for (int i = tid; i < 1024; i += 256) {
    int v = lh[i];
    if (v) atomicAdd(&hist[i], v);
  }
}

__global__ __launch_bounds__(1024) void k_scan(const int* __restrict__ hist,
                                               int* __restrict__ start,
                                               int* __restrict__ cursor) {
  __shared__ int sc[1024];
  int t = threadIdx.x;
  int h = hist[t];
  sc[t] = h;
  __syncthreads();
  for (int off = 1; off < 1024; off <<= 1) {
    int v = (t >= off) ? sc[t - off] : 0;
    __syncthreads();
    sc[t] += v;
    __syncthreads();
  }
  int ex = sc[t] - h;
  start[t] = ex;
  cursor[t] = ex;
}

__global__ __launch_bounds__(256) void k_scatter(const int* __restrict__ mem,
                                                 int* __restrict__ cursor,
                                                 int* __restrict__ list) {
  int i = blockIdx.x * 256 + threadIdx.x;
  if (i < 500000) {
    int pos = atomicAdd(&cursor[mem[i]], 1);
    list[pos] = i;
  }
}

// ---------------- prep: feat fp32[500k x 75] -> fp16 padded [500k x 80] ----------------
__global__ __launch_bounds__(256) void k_prep(const float* __restrict__ feat,
                                              __half2* __restrict__ featH2) {
  int i = blockIdx.x * 256 + threadIdx.x;  // 20,000,000 exactly
  int a = i / 40;
  int jp = i - a * 40;
  int kk = jp * 2;
  float v0 = (kk < 75) ? feat[(size_t)a * 75 + kk] : 0.f;
  float v1 = (kk + 1 < 75) ? feat[(size_t)a * 75 + kk + 1] : 0.f;
  featH2[i] = __floats2half2_rn(v0, v1);
}

// ---------------- prep: W -> fp16 in MFMA B-fragment order ----------------
// Layout per layer: [d][c][ns][lane][j=0..7] where the element is
// B[n][k] = W[k][n], n = ns*16 + (lane&15), k = c*32 + (lane>>4)*8 + j.
__global__ __launch_bounds__(256) void k_prep_w(
    const float* __restrict__ Ws1, const float* __restrict__ Wn1,
    const float* __restrict__ Ws2, const float* __restrict__ Wn2,
    __half* __restrict__ W1H, __half* __restrict__ W2H) {
  int i = blockIdx.x * 256 + threadIdx.x;  // 129024 exactly
  if (i < 71680) {  // layer1: 7 * (5*4*64*8) = 7*10240, KP=160
    int d = i / 10240, r = i - d * 10240;
    int j = r & 7, lane = (r >> 3) & 63, t = r >> 9;  // t = c*4+ns, 0..19
    int n = (t & 3) * 16 + (lane & 15);
    int k = (t >> 2) * 32 + (lane >> 4) * 8 + j;
    float v = 0.f;
    if (k < 75) v = Ws1[d * 4800 + k * 64 + n];
    else if (k >= 80 && k < 155 && d > 0) v = Wn1[(d - 1) * 4800 + (k - 80) * 64 + n];
    W1H[i] = __float2half(v);
  } else {  // layer2: 7 * (4*4*64*8) = 7*8192, KP=128
    int i2 = i - 71680;
    int d = i2 / 8192, r = i2 - d * 8192;
    int j = r & 7, lane = (r >> 3) & 63, t = r >> 9;  // 0..15
    int n = (t & 3) * 16 + (lane & 15);
    int k = (t >> 2) * 32 + (lane >> 4) * 8 + j;
    float v = 0.f;
    if (k < 64) v = Ws2[d * 4096 + k * 64 + n];
    else if (d > 0) v = Wn2[(d - 1) * 4096 + (k - 64) * 64 + n];
    W2H[i2] = __float2half(v);
  }
}

// ---------------- prep: d1_W (64x128 fp32) -> hi/lo fp16 [2][128][64] ----------------
__global__ __launch_bounds__(256) void k_prep_d1(const float* __restrict__ W,
                                                 __half* __restrict__ D1H) {
  int i = blockIdx.x * 256 + threadIdx.x;  // 8192 exactly
  int n = i >> 6, k = i & 63;
  float v = W[k * 128 + n];
  __half hi = __float2half(v);
  D1H[i] = hi;
  D1H[8192 + i] = __float2half(v - __half2float(hi));
}

// ---------------- fused graph_conv (MFMA) + tanh + bn1, fp16 in/out ----------------
// Block = 256 atoms, 4 waves. Staging: (row, 8-half seg) tasks, 16B global loads.
// B frags loaded straight from global (fragment-ordered W, L1/L2-hot). No B LDS.
template<int FP, int NCH, int D>
__device__ __forceinline__ void gcm_run(
    const __half* __restrict__ featH, const int* __restrict__ adj_g,
    int abase, int na, const f16x8* __restrict__ Wf,
    const float* __restrict__ bias_d,
    const float* __restrict__ bng, const float* __restrict__ bnb,
    const float* __restrict__ bnm, const float* __restrict__ bnv,
    __half* __restrict__ out,
    __half* Ac, int* aidx) {
  int tid = threadIdx.x;

  if (D > 0)
    for (int i = tid; i < na * D; i += 256) aidx[i] = adj_g[i];

  int lane = tid & 63, w = tid >> 6;
  int ln = lane & 15, q = lane >> 4;

  float sc[4], sh[4];
  f32x4 acc[4][4];
  #pragma unroll
  for (int ns = 0; ns < 4; ns++) {
    int j = ns * 16 + ln;
    sc[ns] = bng[j] * rsqrtf(bnv[j] + 1e-3f);
    sh[ns] = bnb[j] - bnm[j] * sc[ns];
    float bj = bias_d[j];
    #pragma unroll
    for (int ms = 0; ms < 4; ms++) acc[ms][ns] = (f32x4){bj, bj, bj, bj};
  }

  for (int c = 0; c < NCH; c++) {
    __syncthreads();  // covers aidx staging (c==0) and previous frag reads
    // stage A chunk: 256 rows x 4 segments of 8 halves (16B per lane-task)
    #pragma unroll
    for (int it = 0; it < 4; it++) {
      int idx = it * 256 + tid;
      int m = idx >> 2, sg = idx & 3;
      int ksg = c * 32 + sg * 8;
      f16x8 v = {};
      if (m < na) {
        if (ksg < FP) {
          v = *(const f16x8*)(featH + (size_t)(abase + m) * FP + ksg);
        } else if (D > 0) {
          int kb = ksg - FP;
          const int* ar = aidx + m * D;
          v = *(const f16x8*)(featH + (size_t)ar[0] * FP + kb);
          #pragma unroll
          for (int e = 1; e < D; e++) {
            f16x8 u = *(const f16x8*)(featH + (size_t)ar[e] * FP + kb);
            v = v + u;
          }
        }
      }
      *(f16x8*)(Ac + m * 40 + sg * 8) = v;
    }
    __syncthreads();

    f16x8 af[4], bf[4];
    #pragma unroll
    for (int ms = 0; ms < 4; ms++)
      af[ms] = *(const f16x8*)(Ac + (w * 64 + ms * 16 + ln) * 40 + q * 8);
    #pragma unroll
    for (int ns = 0; ns < 4; ns++)
      bf[ns] = Wf[(c * 4 + ns) * 64 + lane];
    #pragma unroll
    for (int ms = 0; ms < 4; ms++)
      #pragma unroll
      for (int ns = 0; ns < 4; ns++)
        acc[ms][ns] = __builtin_amdgcn_mfma_f32_16x16x32_f16(af[ms], bf[ns], acc[ms][ns], 0, 0, 0);
  }

  // epilogue: tanh + bn, store fp16. D layout: col=lane&15, row=(lane>>4)*4+reg
  #pragma unroll
  for (int ms = 0; ms < 4; ms++) {
    #pragma unroll
    for (int ns = 0; ns < 4; ns++) {
      int j = ns * 16 + ln;
      #pragma unroll
      for (int r = 0; r < 4; r++) {
        int atom = w * 64 + ms * 16 + q * 4 + r;
        if (atom < na)
          out[(size_t)(abase + atom) * 64 + j] =
              __float2half(tanh_fast(acc[ms][ns][r]) * sc[ns] + sh[ns]);
      }
    }
  }
}

template<int FP, int NCH>
__global__ __launch_bounds__(256, 4) void k_gcm(
    const __half* __restrict__ featH, AdjPtrs adjs,
    const __half* __restrict__ WtH, const float* __restrict__ bias,
    const float* __restrict__ bng, const float* __restrict__ bnb,
    const float* __restrict__ bnm, const float* __restrict__ bnv,
    __half* __restrict__ out) {
  __shared__ __align__(16) __half Ac[256 * 40];
  __shared__ int aidx[256 * 6];

  int bid = blockIdx.x;
  int d, off, end, bloc;
  if      (bid < 79)   { d = 0; bloc = bid;        off = 0;      end = 20000;  }
  else if (bid < 392)  { d = 1; bloc = bid - 79;   off = 20000;  end = 100000; }
  else if (bid < 978)  { d = 2; bloc = bid - 392;  off = 100000; end = 250000; }
  else if (bid < 1564) { d = 3; bloc = bid - 978;  off = 250000; end = 400000; }
  else if (bid < 1857) { d = 4; bloc = bid - 1564; off = 400000; end = 475000; }
  else if (bid < 1936) { d = 5; bloc = bid - 1857; off = 475000; end = 495000; }
  else                 { d = 6; bloc = bid - 1936; off = 495000; end = 500000; }
  int abase = off + bloc * 256;
  int na = min(256, end - abase);
  const int* adj_g = (d > 0) ? adjs.p[d - 1] + (abase - off) * d : (const int*)0;
  const f16x8* Wf = (const f16x8*)WtH + d * (NCH * 4 * 64);
  const float* bias_d = bias + d * 64;

  switch (d) {
    case 0: gcm_run<FP, NCH, 0>(featH, adj_g, abase, na, Wf, bias_d, bng, bnb, bnm, bnv, out, Ac, aidx); break;
    case 1: gcm_run<FP, NCH, 1>(featH, adj_g, abase, na, Wf, bias_d, bng, bnb, bnm, bnv, out, Ac, aidx); break;
    case 2: gcm_run<FP, NCH, 2>(featH, adj_g, abase, na, Wf, bias_d, bng, bnb, bnm, bnv, out, Ac, aidx); break;
    case 3: gcm_run<FP, NCH, 3>(featH, adj_g, abase, na, Wf, bias_d, bng, bnb, bnm, bnv, out, Ac, aidx); break;
    case 4: gcm_run<FP, NCH, 4>(featH, adj_g, abase, na, Wf, bias_d, bng, bnb, bnm, bnv, out, Ac, aidx); break;
    case 5: gcm_run<FP, NCH, 5>(featH, adj_g, abase, na, Wf, bias_d, bng, bnb, bnm, bnv, out, Ac, aidx); break;
    default: gcm_run<FP, NCH, 6>(featH, adj_g, abase, na, Wf, bias_d, bng, bnb, bnm, bnv, out, Ac, aidx); break;
  }
}

// ---------------- graph_pool fp16, 16B segments + packed max ----------------
template<int D>
__device__ __forceinline__ f16x8 pool_h_acc(const f16x8* __restrict__ in8,
                                            const int* __restrict__ ad, int sg, f16x8 v) {
  #pragma unroll
  for (int e = 0; e < D; e++) v = max8(v, in8[ad[e] * 8 + sg]);
  return v;
}

__global__ __launch_bounds__(256) void k_pool_h(const f16x8* __restrict__ in8, AdjPtrs adjs,
                                                f16x8* __restrict__ out8) {
  int t = blockIdx.x * 256 + threadIdx.x;  // 4,000,000 exactly
  int atom = t >> 3, sg = t & 7;
  int d, off;
  if      (atom < 20000)  { d = 0; off = 0;      }
  else if (atom < 100000) { d = 1; off = 20000;  }
  else if (atom < 250000) { d = 2; off = 100000; }
  else if (atom < 400000) { d = 3; off = 250000; }
  else if (atom < 475000) { d = 4; off = 400000; }
  else if (atom < 495000) { d = 5; off = 475000; }
  else                    { d = 6; off = 495000; }
  f16x8 v = in8[atom * 8 + sg];
  if (d > 0) {
    const int* ad = adjs.p[d - 1] + (atom - off) * d;
    switch (d) {
      case 1: v = pool_h_acc<1>(in8, ad, sg, v); break;
      case 2: v = pool_h_acc<2>(in8, ad, sg, v); break;
      case 3: v = pool_h_acc<3>(in8, ad, sg, v); break;
      case 4: v = pool_h_acc<4>(in8, ad, sg, v); break;
      case 5: v = pool_h_acc<5>(in8, ad, sg, v); break;
      default: v = pool_h_acc<6>(in8, ad, sg, v); break;
    }
  }
  out8[atom * 8 + sg] = v;
}

// ---------------- fused dense1(MFMA, hi/lo W) + tanh + bn3 + segment sum/max + tanh ----
__global__ __launch_bounds__(256, 3) void k_dense1f(
    const __half2* __restrict__ hD2, const int* __restrict__ list,
    const int* __restrict__ start, const int* __restrict__ hist,
    const __half* __restrict__ D1H, const float* __restrict__ d1b,
    const float* __restrict__ g3, const float* __restrict__ b3,
    const float* __restrict__ m3, const float* __restrict__ v3,
    float* __restrict__ g) {
  __shared__ __align__(16) __half Bt[2][128 * 72];
  __shared__ __align__(16) __half Ac[64 * 72];
  int b = blockIdx.x, tid = threadIdx.x;
  int stt = start[b], cnt = hist[b];

  for (int i = tid; i < 8192; i += 256) {
    int n = i >> 6, k = i & 63;
    Bt[0][n * 72 + k] = D1H[i];
    Bt[1][n * 72 + k] = D1H[8192 + i];
  }

  int lane = tid & 63, w = tid >> 6;
  int ln = lane & 15, q = lane >> 4;

  float bj[2], sc[2], sh[2];
  #pragma unroll
  for (int nf = 0; nf < 2; nf++) {
    int col = w * 32 + nf * 16 + ln;
    bj[nf] = d1b[col];
    sc[nf] = g3[col] * rsqrtf(v3[col] + 1e-3f);
    sh[nf] = b3[col] - m3[col] * sc[nf];
  }

  float sum[2] = {0.f, 0.f};
  float mx[2] = {-INFINITY, -INFINITY};

  for (int cb = 0; cb < cnt; cb += 64) {
    int nr = min(64, cnt - cb);
    __syncthreads();  // covers W staging (1st iter) + prior Ac readers
    {
      int r = tid >> 2;
      #pragma unroll
      for (int it = 0; it < 2; it++) {
        int sg = (tid & 3) + it * 4;  // 8-half (16 B) segment
        __half2* dst = (__half2*)(Ac + r * 72 + sg * 8);
        if (r < nr) {
          int a = list[stt + cb + r];
          const __half2* src = hD2 + (size_t)a * 32 + sg * 4;
          __half2 v0 = src[0], v1 = src[1], v2 = src[2], v3h = src[3];
          dst[0] = v0; dst[1] = v1; dst[2] = v2; dst[3] = v3h;
        } else {
          __half2 z = __floats2half2_rn(0.f, 0.f);
          dst[0] = z; dst[1] = z; dst[2] = z; dst[3] = z;
        }
      }
    }
    __syncthreads();

    f32x4 acc[4][2];
    #pragma unroll
    for (int mf = 0; mf < 4; mf++)
      #pragma unroll
      for (int nf = 0; nf < 2; nf++) acc[mf][nf] = (f32x4){bj[nf], bj[nf], bj[nf], bj[nf]};

    #pragma unroll
    for (int hl = 1; hl >= 0; hl--) {
      #pragma unroll
      for (int ks = 0; ks < 2; ks++) {
        f16x8 af[4], bf[2];
        #pragma unroll
        for (int mf = 0; mf < 4; mf++)
          af[mf] = *(const f16x8*)(Ac + (mf * 16 + ln) * 72 + ks * 32 + q * 8);
        #pragma unroll
        for (int nf = 0; nf < 2; nf++)
          bf[nf] = *(const f16x8*)(&Bt[hl][(w * 32 + nf * 16 + ln) * 72 + ks * 32 + q * 8]);
        #pragma unroll
        for (int mf = 0; mf < 4; mf++)
          #pragma unroll
          for (int nf = 0; nf < 2; nf++)
            acc[mf][nf] = __builtin_amdgcn_mfma_f32_16x16x32_f16(af[mf], bf[nf], acc[mf][nf], 0, 0, 0);
      }
    }

    #pragma unroll
    for (int mf = 0; mf < 4; mf++) {
      #pragma unroll
      for (int nf = 0; nf < 2; nf++) {
        #pragma unroll
        for (int r = 0; r < 4; r++) {
          int row = mf * 16 + q * 4 + r;
          if (row < nr) {
            float v = tanh_fast(acc[mf][nf][r]) * sc[nf] + sh[nf];
            sum[nf] += v;
            mx[nf] = fmaxf(mx[nf], v);
          }
        }
      }
    }
  }

  #pragma unroll
  for (int nf = 0; nf < 2; nf++) {
    sum[nf] += __shfl_xor(sum[nf], 16);
    sum[nf] += __shfl_xor(sum[nf], 32);
    mx[nf] = fmaxf(mx[nf], __shfl_xor(mx[nf], 16));
    mx[nf] = fmaxf(mx[nf], __shfl_xor(mx[nf], 32));
  }
  if (q == 0) {
    #pragma unroll
    for (int nf = 0; nf < 2; nf++) {
      int col = w * 32 + nf * 16 + ln;
      g[b * 256 + col] = tanh_fast(sum[nf]);
      g[b * 256 + 128 + col] = tanh_fast(mx[nf]);
    }
  }
}

// ---------------- dense2 -> sigmoid -> dense3 ----------------
__global__ __launch_bounds__(64) void k_dense23(
    const float* __restrict__ g, const float* __restrict__ W2,
    const float* __restrict__ b2, const float* __restrict__ W3,
    const float* __restrict__ b3, float* __restrict__ out) {
  __shared__ float gr[256];
  int b = blockIdx.x, j = threadIdx.x;
  ((float4*)gr)[j] = ((const float4*)(g + b * 256))[j];
  __syncthreads();
  float acc = b2[j];
  #pragma unroll 8
  for (int k = 0; k < 256; k++) acc += gr[k] * W2[k * 64 + j];
  float sg = 1.f / (1.f + expf(-acc));
  float p = sg * W3[j];
  #pragma unroll
  for (int off = 32; off >= 1; off >>= 1) p += __shfl_xor(p, off);
  if (j == 0) out[b] = p + b3[0];
}

// ---------------- launch ----------------
extern "C" void kernel_launch(void* const* d_in, const int* in_sizes, int n_in,
                              void* d_out, int out_size, void* d_ws, size_t ws_size,
                              hipStream_t stream) {
  const float* feat = (const float*)d_in[0];
  const int*   mem  = (const int*)d_in[1];
  AdjPtrs adjs;
  for (int i = 0; i < 6; i++) adjs.p[i] = (const int*)d_in[2 + i];
  const float* gc1_Wn = (const float*)d_in[8];
  const float* gc1_Ws = (const float*)d_in[9];
  const float* gc1_b  = (const float*)d_in[10];
  const float* gc2_Wn = (const float*)d_in[11];
  const float* gc2_Ws = (const float*)d_in[12];
  const float* gc2_b  = (const float*)d_in[13];
  const float* bn1g = (const float*)d_in[14];
  const float* bn1b = (const float*)d_in[15];
  const float* bn1m = (const float*)d_in[16];
  const float* bn1v = (const float*)d_in[17];
  const float* bn3g = (const float*)d_in[18];
  const float* bn3b = (const float*)d_in[19];
  const float* bn3m = (const float*)d_in[20];
  const float* bn3v = (const float*)d_in[21];
  const float* d1W = (const float*)d_in[22];
  const float* d1b = (const float*)d_in[23];
  const float* d2W = (const float*)d_in[24];
  const float* d2b = (const float*)d_in[25];
  const float* d3W = (const float*)d_in[26];
  const float* d3b = (const float*)d_in[27];
  float* out = (float*)d_out;

  char* w = (char*)d_ws;
  __half* featH = (__half*)(w);
  __half* hA    = (__half*)(w + 80000000LL);
  __half* hB    = (__half*)(w + 144000000LL);
  __half* hC    = (__half*)(w);              // gc2 out (featH dead)
  __half* hD    = (__half*)(w + 80000000LL); // pool2 out (hA dead)
  __half* W1H   = (__half*)(w + 210000000LL);
  __half* W2H   = (__half*)(w + 210200000LL);
  __half* D1H   = (__half*)(w + 210330000LL);  // 32 KB hi/lo
  float*  g     = (float*)(w + 210400000LL);   // 1 MB
  int* hist     = (int*)(w + 211600000LL);
  int* start    = (int*)(w + 211604096LL);
  int* cursor   = (int*)(w + 211608192LL);
  int* list     = (int*)(w + 211612288LL);     // 2 MB

  // membership counting sort
  k_zero_hist<<<4, 256, 0, stream>>>(hist);
  k_hist<<<512, 256, 0, stream>>>(mem, hist);
  k_scan<<<1, 1024, 0, stream>>>(hist, start, cursor);
  k_scatter<<<1954, 256, 0, stream>>>(mem, cursor, list);

  // prep
  k_prep<<<78125, 256, 0, stream>>>(feat, (__half2*)featH);
  k_prep_w<<<504, 256, 0, stream>>>(gc1_Ws, gc1_Wn, gc2_Ws, gc2_Wn, W1H, W2H);
  k_prep_d1<<<32, 256, 0, stream>>>(d1W, D1H);

  // main pipeline
  k_gcm<80, 5><<<1956, 256, 0, stream>>>(featH, adjs, W1H, gc1_b,
                                         bn1g, bn1b, bn1m, bn1v, hA);
  k_pool_h<<<15625, 256, 0, stream>>>((const f16x8*)hA, adjs, (f16x8*)hB);
  k_gcm<64, 4><<<1956, 256, 0, stream>>>(hB, adjs, W2H, gc2_b,
                                         bn1g, bn1b, bn1m, bn1v, hC);
  k_pool_h<<<15625, 256, 0, stream>>>((const f16x8*)hC, adjs, (f16x8*)hD);
  k_dense1f<<<1024, 256, 0, stream>>>((const __half2*)hD, list, start, hist, D1H, d1b,
                                      bn3g, bn3b, bn3m, bn3v, g);
  k_dense23<<<1024, 64, 0, stream>>>(g, d2W, d2b, d3W, d3b, out);
}